// Round 1
// baseline (5506.524 us; speedup 1.0000x reference)
//
#include <hip/hip_runtime.h>

#define N_NODES 100000
#define N_EDGES 50000
#define C 128

// One 32-lane group per nonzero: gather one 512B row from src, atomically add
// into one 512B row of dst. 8 rows per 256-thread block.
__global__ __launch_bounds__(256) void scatter_rows(
    const float4* __restrict__ src,        // [n_src_rows][32] as float4
    const int* __restrict__ gather_idx,    // row index into src, per nz
    const int* __restrict__ scatter_idx,   // row index into dst, per nz
    float* __restrict__ dst, int nnz)
{
    int gid  = blockIdx.x * 256 + threadIdx.x;
    int row  = gid >> 5;
    int lane = gid & 31;
    if (row >= nnz) return;
    int g = gather_idx[row];
    int s = scatter_idx[row];
    float4 v = src[(size_t)g * 32 + lane];
    float* d = dst + (size_t)s * C + lane * 4;
    atomicAdd(d + 0, v.x);
    atomicAdd(d + 1, v.y);
    atomicAdd(d + 2, v.z);
    atomicAdd(d + 3, v.w);
}

// out[row][col] = sum_k (x0[row][k] + m[row][k]) * W[col][k] + b[col]
// Block: 256 threads -> 32 rows x 128 cols. Thread: col = t&127, 16 rows.
__global__ __launch_bounds__(256) void gin_gemm(
    const float* __restrict__ x0, const float* __restrict__ m,
    const float* __restrict__ W, const float* __restrict__ b,
    float* __restrict__ out)
{
    __shared__ float Ws[32][129];   // [k_local][col], padded
    __shared__ float ins[32][33];   // [row_local][k_local], padded

    int t   = threadIdx.x;
    int col = t & 127;
    int rg  = t >> 7;               // 0..1 (row-group of 16)
    int row0 = blockIdx.x * 32;

    float acc[16];
#pragma unroll
    for (int r = 0; r < 16; ++r) acc[r] = 0.f;
    float bias = b[col];

    for (int kt = 0; kt < C; kt += 32) {
        // Stage W-tile: W[wc][kt+kl] -> Ws[kl][wc]; 4096 floats, 16/thread.
#pragma unroll
        for (int j = 0; j < 16; ++j) {
            int i  = j * 256 + t;
            int wc = i >> 5;
            int kl = i & 31;
            Ws[kl][wc] = W[(size_t)wc * C + kt + kl];
        }
        // Stage input tile: (x0+m)[row0+r][kt+kl] -> ins[r][kl]; 1024 floats.
#pragma unroll
        for (int j = 0; j < 4; ++j) {
            int i  = j * 256 + t;
            int r  = i >> 5;
            int kl = i & 31;
            size_t gi = (size_t)(row0 + r) * C + kt + kl;
            ins[r][kl] = x0[gi] + m[gi];
        }
        __syncthreads();
#pragma unroll
        for (int kl = 0; kl < 32; ++kl) {
            float wv = Ws[kl][col];
#pragma unroll
            for (int r = 0; r < 16; ++r)
                acc[r] += ins[rg * 16 + r][kl] * wv;
        }
        __syncthreads();
    }
#pragma unroll
    for (int r = 0; r < 16; ++r)
        out[(size_t)(row0 + rg * 16 + r) * C + col] = acc[r] + bias;
}

extern "C" void kernel_launch(void* const* d_in, const int* in_sizes, int n_in,
                              void* d_out, int out_size, void* d_ws, size_t ws_size,
                              hipStream_t stream) {
    const float* x0  = (const float*)d_in[0];
    const int* nidx  = (const int*)d_in[1];
    const int* eidx  = (const int*)d_in[2];
    const float* W   = (const float*)d_in[3];
    const float* b   = (const float*)d_in[4];

    float* out0 = (float*)d_out;
    float* x1   = out0 + (size_t)N_NODES * C;   // second output chunk
    float* m    = (float*)d_ws;                 // scratch: N_NODES x C

    int nnz = in_sizes[1];

    // Zero the accumulation targets every call (d_out/d_ws arrive poisoned).
    hipMemsetAsync(x1, 0, (size_t)N_EDGES * C * sizeof(float), stream);
    hipMemsetAsync(m,  0, (size_t)N_NODES * C * sizeof(float), stream);

    int blocks = (nnz + 7) / 8;   // 8 nz-rows per block

    // Step 1: x_1[e] += x_0[n]  for each (n, e)
    scatter_rows<<<blocks, 256, 0, stream>>>(
        (const float4*)x0, nidx, eidx, x1, nnz);

    // Step 2: m[n] += x_1[e]  for each (n, e)
    scatter_rows<<<blocks, 256, 0, stream>>>(
        (const float4*)x1, eidx, nidx, m, nnz);

    // Step 3: out_0 = (x_0 + m) @ W^T + b
    gin_gemm<<<N_NODES / 32, 256, 0, stream>>>(x0, m, W, b, out0);
}

// Round 2
// 1086.185 us; speedup vs baseline: 5.0696x; 5.0696x over previous
//
#include <hip/hip_runtime.h>

#define N_NODES 100000
#define N_EDGES 50000
#define C 128

// ---------------- CSR build ----------------

__global__ __launch_bounds__(256) void hist_kernel(
    const int* __restrict__ nidx, const int* __restrict__ eidx,
    int* __restrict__ ncnt, int* __restrict__ ecnt, int nnz)
{
    for (int i = blockIdx.x * 256 + threadIdx.x; i < nnz; i += gridDim.x * 256) {
        atomicAdd(&ecnt[eidx[i]], 1);
        atomicAdd(&ncnt[nidx[i]], 1);
    }
}

// Single-block exclusive scan: cnt[0..n) -> off[0..n], and a cursor copy.
__global__ __launch_bounds__(1024) void scan_kernel(
    const int* __restrict__ cnt, int* __restrict__ off,
    int* __restrict__ cur, int n)
{
    __shared__ int s[1024];
    int t = threadIdx.x;
    int K = (n + 1023) >> 10;
    int lo = t * K, hi = lo + K;
    if (lo > n) lo = n;
    if (hi > n) hi = n;

    int sum = 0;
    for (int i = lo; i < hi; ++i) sum += cnt[i];
    s[t] = sum;
    __syncthreads();
    for (int d = 1; d < 1024; d <<= 1) {
        int v = (t >= d) ? s[t - d] : 0;
        __syncthreads();
        s[t] += v;
        __syncthreads();
    }
    int run = s[t] - sum;   // exclusive prefix of this thread's chunk
    for (int i = lo; i < hi; ++i) {
        off[i] = run;
        cur[i] = run;
        run += cnt[i];
    }
    if (t == 1023) off[n] = s[1023];
}

__global__ __launch_bounds__(256) void fill_kernel(
    const int* __restrict__ nidx, const int* __restrict__ eidx,
    int* __restrict__ ecur, int* __restrict__ ncur,
    int* __restrict__ e_list, int* __restrict__ n_list, int nnz)
{
    for (int i = blockIdx.x * 256 + threadIdx.x; i < nnz; i += gridDim.x * 256) {
        int n = nidx[i], e = eidx[i];
        int p = atomicAdd(&ecur[e], 1);
        e_list[p] = n;                  // nodes belonging to edge e
        int q = atomicAdd(&ncur[n], 1);
        n_list[q] = e;                  // edges incident to node n
    }
}

// ---------------- segment sum: one wave (64 lanes) per output row ----------------
// dst[seg][c] = sum over members g of src[g][c].  Row = 128 f32 = 64 float2.
__global__ __launch_bounds__(256) void seg_sum(
    const float2* __restrict__ src, const int* __restrict__ list,
    const int* __restrict__ off, float2* __restrict__ dst, int nseg)
{
    int wid  = (blockIdx.x * 256 + threadIdx.x) >> 6;
    int lane = threadIdx.x & 63;
    if (wid >= nseg) return;
    int s0 = off[wid], s1 = off[wid + 1];
    float2 acc = make_float2(0.f, 0.f);
    for (int base = s0; base < s1; base += 64) {
        int cnt = s1 - base; if (cnt > 64) cnt = 64;
        int my = (lane < cnt) ? list[base + lane] : 0;
        for (int j = 0; j < cnt; ++j) {
            int g = __shfl(my, j);
            float2 v = src[(size_t)g * 64 + lane];
            acc.x += v.x; acc.y += v.y;
        }
    }
    dst[(size_t)wid * 64 + lane] = acc;
}

// ---------------- fallback atomic scatter (round-1 path) ----------------
__global__ __launch_bounds__(256) void scatter_rows(
    const float4* __restrict__ src, const int* __restrict__ gather_idx,
    const int* __restrict__ scatter_idx, float* __restrict__ dst, int nnz)
{
    int gid = blockIdx.x * 256 + threadIdx.x;
    int row = gid >> 5, lane = gid & 31;
    if (row >= nnz) return;
    float4 v = src[(size_t)gather_idx[row] * 32 + lane];
    float* d = dst + (size_t)scatter_idx[row] * C + lane * 4;
    atomicAdd(d + 0, v.x); atomicAdd(d + 1, v.y);
    atomicAdd(d + 2, v.z); atomicAdd(d + 3, v.w);
}

// ---------------- GIN GEMM: out = (x0 + m) @ W^T + b ----------------
__global__ __launch_bounds__(256) void gin_gemm(
    const float* __restrict__ x0, const float* __restrict__ m,
    const float* __restrict__ W, const float* __restrict__ b,
    float* __restrict__ out)
{
    __shared__ float Ws[32][129];
    __shared__ float ins[32][33];
    int t = threadIdx.x;
    int col = t & 127, rg = t >> 7;
    int row0 = blockIdx.x * 32;
    float acc[16];
#pragma unroll
    for (int r = 0; r < 16; ++r) acc[r] = 0.f;
    float bias = b[col];
    for (int kt = 0; kt < C; kt += 32) {
#pragma unroll
        for (int j = 0; j < 16; ++j) {
            int i = j * 256 + t, wc = i >> 5, kl = i & 31;
            Ws[kl][wc] = W[(size_t)wc * C + kt + kl];
        }
#pragma unroll
        for (int j = 0; j < 4; ++j) {
            int i = j * 256 + t, r = i >> 5, kl = i & 31;
            size_t gi = (size_t)(row0 + r) * C + kt + kl;
            ins[r][kl] = x0[gi] + m[gi];
        }
        __syncthreads();
#pragma unroll
        for (int kl = 0; kl < 32; ++kl) {
            float wv = Ws[kl][col];
#pragma unroll
            for (int r = 0; r < 16; ++r)
                acc[r] += ins[rg * 16 + r][kl] * wv;
        }
        __syncthreads();
    }
#pragma unroll
    for (int r = 0; r < 16; ++r)
        out[(size_t)(row0 + rg * 16 + r) * C + col] = acc[r] + bias;
}

extern "C" void kernel_launch(void* const* d_in, const int* in_sizes, int n_in,
                              void* d_out, int out_size, void* d_ws, size_t ws_size,
                              hipStream_t stream) {
    const float* x0 = (const float*)d_in[0];
    const int* nidx = (const int*)d_in[1];
    const int* eidx = (const int*)d_in[2];
    const float* W  = (const float*)d_in[3];
    const float* b  = (const float*)d_in[4];

    float* out0 = (float*)d_out;
    float* x1   = out0 + (size_t)N_NODES * C;
    int nnz = in_sizes[1];

    // ---- workspace layout ----
    char* p = (char*)d_ws;
    float* m    = (float*)p;  p += (size_t)N_NODES * C * sizeof(float);
    int* e_list = (int*)p;    p += (size_t)nnz * sizeof(int);
    int* n_list = (int*)p;    p += (size_t)nnz * sizeof(int);
    int* ecnt   = (int*)p;    p += (size_t)N_EDGES * sizeof(int);   // ecnt+ncnt contiguous
    int* ncnt   = (int*)p;    p += (size_t)N_NODES * sizeof(int);   //   -> one memset
    int* ecur   = (int*)p;    p += (size_t)N_EDGES * sizeof(int);
    int* ncur   = (int*)p;    p += (size_t)N_NODES * sizeof(int);
    int* eoff   = (int*)p;    p += (size_t)(N_EDGES + 1) * sizeof(int);
    int* noff   = (int*)p;    p += (size_t)(N_NODES + 1) * sizeof(int);
    size_t needed = (size_t)(p - (char*)d_ws);

    if (ws_size < needed) {
        // Fallback: atomic scatter path (correct, slower).
        hipMemsetAsync(x1, 0, (size_t)N_EDGES * C * sizeof(float), stream);
        hipMemsetAsync(m,  0, (size_t)N_NODES * C * sizeof(float), stream);
        int blocks = (nnz + 7) / 8;
        scatter_rows<<<blocks, 256, 0, stream>>>((const float4*)x0, nidx, eidx, x1, nnz);
        scatter_rows<<<blocks, 256, 0, stream>>>((const float4*)x1, eidx, nidx, m, nnz);
        gin_gemm<<<N_NODES / 32, 256, 0, stream>>>(x0, m, W, b, out0);
        return;
    }

    // ---- CSR build ----
    hipMemsetAsync(ecnt, 0, (size_t)(N_EDGES + N_NODES) * sizeof(int), stream);
    hist_kernel<<<2048, 256, 0, stream>>>(nidx, eidx, ncnt, ecnt, nnz);
    scan_kernel<<<1, 1024, 0, stream>>>(ecnt, eoff, ecur, N_EDGES);
    scan_kernel<<<1, 1024, 0, stream>>>(ncnt, noff, ncur, N_NODES);
    fill_kernel<<<2048, 256, 0, stream>>>(nidx, eidx, ecur, ncur, e_list, n_list, nnz);

    // ---- step 1: x1[e] = sum_{n in e} x0[n] ----
    seg_sum<<<(N_EDGES * 64 + 255) / 256, 256, 0, stream>>>(
        (const float2*)x0, e_list, eoff, (float2*)x1, N_EDGES);

    // ---- step 2: m[n] = sum_{e ∋ n} x1[e] ----
    seg_sum<<<(N_NODES * 64 + 255) / 256, 256, 0, stream>>>(
        (const float2*)x1, n_list, noff, (float2*)m, N_NODES);

    // ---- step 3: out0 = (x0 + m) @ W^T + b ----
    gin_gemm<<<N_NODES / 32, 256, 0, stream>>>(x0, m, W, b, out0);
}

// Round 3
// 997.275 us; speedup vs baseline: 5.5216x; 1.0892x over previous
//
#include <hip/hip_runtime.h>
#include <stdint.h>

#define N_NODES 100000
#define N_EDGES 50000
#define C 128
#define NB 196        // coarse buckets: ceil(50000/256) == ceil(100000/512)
#define CAP 12288     // LDS staging entries per bucket (48KB)

// ---------------- exact histograms ----------------
__global__ __launch_bounds__(256) void hist_kernel(
    const int* __restrict__ nidx, const int* __restrict__ eidx,
    int* __restrict__ ncnt, int* __restrict__ ecnt, int nnz)
{
    for (int i = blockIdx.x * 256 + threadIdx.x; i < nnz; i += gridDim.x * 256) {
        atomicAdd(&ecnt[eidx[i]], 1);
        atomicAdd(&ncnt[nidx[i]], 1);
    }
}

// ---------------- single-block exclusive scan ----------------
__global__ __launch_bounds__(1024) void scan_kernel(
    const int* __restrict__ cnt, int* __restrict__ off,
    int* __restrict__ cur, int n)
{
    __shared__ int s[1024];
    int t = threadIdx.x;
    int K = (n + 1023) >> 10;
    int lo = t * K, hi = lo + K;
    if (lo > n) lo = n;
    if (hi > n) hi = n;
    int sum = 0;
    for (int i = lo; i < hi; ++i) sum += cnt[i];
    s[t] = sum;
    __syncthreads();
    for (int d = 1; d < 1024; d <<= 1) {
        int v = (t >= d) ? s[t - d] : 0;
        __syncthreads();
        s[t] += v;
        __syncthreads();
    }
    int run = s[t] - sum;
    for (int i = lo; i < hi; ++i) {
        off[i] = run;
        if (cur) cur[i] = run;
        run += cnt[i];
    }
    if (t == 1023) off[n] = s[1023];
}

// Coarse-bucket cursors are just exact offsets at bucket boundaries.
__global__ void init_cursors(const int* __restrict__ eoff, const int* __restrict__ noff,
                             int* __restrict__ Cecur, int* __restrict__ Cncur)
{
    int t = threadIdx.x;
    if (t < NB) {
        Cecur[t] = eoff[t * 256];
        Cncur[t] = noff[t * 512];
    }
}

// ---------------- phase B1: partition pairs into coarse buckets ----------------
// Bucket for e: e>>8 (256 keys/bucket). Bucket for n: n>>9 (512 keys/bucket).
// Per block: LDS histogram -> reserve global range -> ranked burst writes.
__global__ __launch_bounds__(256) void partition_kernel(
    const int* __restrict__ nidx, const int* __restrict__ eidx,
    int* __restrict__ Cecur, int* __restrict__ Cncur,
    uint64_t* __restrict__ pe, uint64_t* __restrict__ pn, int nnz)
{
    __shared__ int he[NB], hn[NB], be[NB], bn[NB];
    int t = threadIdx.x;
    int chunk0 = blockIdx.x * 4096;
    for (int k = t; k < NB; k += 256) { he[k] = 0; hn[k] = 0; }
    __syncthreads();
#pragma unroll 4
    for (int j = 0; j < 16; ++j) {
        int i = chunk0 + j * 256 + t;
        if (i < nnz) {
            atomicAdd(&he[eidx[i] >> 8], 1);
            atomicAdd(&hn[nidx[i] >> 9], 1);
        }
    }
    __syncthreads();
    for (int k = t; k < NB; k += 256) {
        be[k] = atomicAdd(&Cecur[k], he[k]);
        bn[k] = atomicAdd(&Cncur[k], hn[k]);
        he[k] = 0; hn[k] = 0;
    }
    __syncthreads();
#pragma unroll 4
    for (int j = 0; j < 16; ++j) {
        int i = chunk0 + j * 256 + t;
        if (i < nnz) {
            int e = eidx[i], n = nidx[i];
            int re = atomicAdd(&he[e >> 8], 1);
            pe[be[e >> 8] + re] = ((uint64_t)e << 32) | (uint32_t)n;
            int rn = atomicAdd(&hn[n >> 9], 1);
            pn[bn[n >> 9] + rn] = ((uint64_t)n << 32) | (uint32_t)e;
        }
    }
}

// ---------------- phase B2: within-bucket exact scatter via LDS, coalesced out ----------------
__global__ __launch_bounds__(256) void bucket_scatter(
    const uint64_t* __restrict__ pairs, const int* __restrict__ off,
    int* __restrict__ out, int kpb, int nkeys)
{
    __shared__ int cursor[512];
    __shared__ int vals[CAP];
    int t = threadIdx.x;
    int key0 = blockIdx.x * kpb;
    int key1 = key0 + kpb; if (key1 > nkeys) key1 = nkeys;
    int start = off[key0], end = off[key1];
    for (int k = t; k < key1 - key0; k += 256) cursor[k] = off[key0 + k] - start;
    __syncthreads();
    for (int i = start + t; i < end; i += 256) {
        uint64_t p = pairs[i];
        int key = (int)(p >> 32);
        int val = (int)(uint32_t)p;
        int pos = atomicAdd(&cursor[key - key0], 1);
        if (pos < CAP) vals[pos] = val;
        else out[start + pos] = val;       // rare spill, still correct
    }
    __syncthreads();
    int sz = end - start; if (sz > CAP) sz = CAP;
    for (int j = t; j < sz; j += 256) out[start + j] = vals[j];
}

// ---------------- segment sum: one wave per output row ----------------
__global__ __launch_bounds__(256) void seg_sum(
    const float2* __restrict__ src, const int* __restrict__ list,
    const int* __restrict__ off, float2* __restrict__ dst, int nseg)
{
    int wid  = (blockIdx.x * 256 + threadIdx.x) >> 6;
    int lane = threadIdx.x & 63;
    if (wid >= nseg) return;
    int s0 = off[wid], s1 = off[wid + 1];
    float2 acc = make_float2(0.f, 0.f);
    for (int base = s0; base < s1; base += 64) {
        int cnt = s1 - base; if (cnt > 64) cnt = 64;
        int my = (lane < cnt) ? list[base + lane] : 0;
        for (int j = 0; j < cnt; ++j) {
            int g = __shfl(my, j);
            float2 v = src[(size_t)g * 64 + lane];
            acc.x += v.x; acc.y += v.y;
        }
    }
    dst[(size_t)wid * 64 + lane] = acc;
}

// ---------------- fused: m-gather + GIN GEMM ----------------
// Block = 32 nodes. Phase 1: 4 waves gather-sum x1 rows + x0 into LDS ins.
// Phase 2: out[row][col] = sum_k ins[row][k] * W[col][k] + b[col].
__global__ __launch_bounds__(256) void gin_fused(
    const float2* __restrict__ x0, const float2* __restrict__ x1,
    const int* __restrict__ n_list, const int* __restrict__ noff,
    const float* __restrict__ W, const float* __restrict__ b,
    float* __restrict__ out)
{
    __shared__ float ins[32][130];
    __shared__ float Ws[32][129];
    int t = threadIdx.x;
    int lane = t & 63, w = t >> 6;      // 4 waves
    int row0 = blockIdx.x * 32;

    for (int r = w * 8; r < w * 8 + 8; ++r) {
        int node = row0 + r;
        int s0 = noff[node], s1 = noff[node + 1];
        float2 acc = x0[(size_t)node * 64 + lane];
        for (int base = s0; base < s1; base += 64) {
            int cnt = s1 - base; if (cnt > 64) cnt = 64;
            int my = (lane < cnt) ? n_list[base + lane] : 0;
            for (int j = 0; j < cnt; ++j) {
                int g = __shfl(my, j);
                float2 v = x1[(size_t)g * 64 + lane];
                acc.x += v.x; acc.y += v.y;
            }
        }
        ins[r][lane * 2]     = acc.x;
        ins[r][lane * 2 + 1] = acc.y;
    }
    __syncthreads();

    int col = t & 127, rg = t >> 7;
    float acc[16];
#pragma unroll
    for (int r = 0; r < 16; ++r) acc[r] = 0.f;
    float bias = b[col];
    for (int kt = 0; kt < C; kt += 32) {
#pragma unroll
        for (int j = 0; j < 16; ++j) {
            int i = j * 256 + t, wc = i >> 5, kl = i & 31;
            Ws[kl][wc] = W[(size_t)wc * C + kt + kl];
        }
        __syncthreads();
#pragma unroll
        for (int kl = 0; kl < 32; ++kl) {
            float wv = Ws[kl][col];
#pragma unroll
            for (int r = 0; r < 16; ++r)
                acc[r] += ins[rg * 16 + r][kt + kl] * wv;
        }
        __syncthreads();
    }
#pragma unroll
    for (int r = 0; r < 16; ++r)
        out[(size_t)(row0 + rg * 16 + r) * C + col] = acc[r] + bias;
}

// ---------------- fallback atomic path ----------------
__global__ __launch_bounds__(256) void scatter_rows(
    const float4* __restrict__ src, const int* __restrict__ gather_idx,
    const int* __restrict__ scatter_idx, float* __restrict__ dst, int nnz)
{
    int gid = blockIdx.x * 256 + threadIdx.x;
    int row = gid >> 5, lane = gid & 31;
    if (row >= nnz) return;
    float4 v = src[(size_t)gather_idx[row] * 32 + lane];
    float* d = dst + (size_t)scatter_idx[row] * C + lane * 4;
    atomicAdd(d + 0, v.x); atomicAdd(d + 1, v.y);
    atomicAdd(d + 2, v.z); atomicAdd(d + 3, v.w);
}

__global__ __launch_bounds__(256) void gin_gemm(
    const float* __restrict__ x0, const float* __restrict__ m,
    const float* __restrict__ W, const float* __restrict__ b,
    float* __restrict__ out)
{
    __shared__ float Ws[32][129];
    __shared__ float ins[32][33];
    int t = threadIdx.x;
    int col = t & 127, rg = t >> 7;
    int row0 = blockIdx.x * 32;
    float acc[16];
#pragma unroll
    for (int r = 0; r < 16; ++r) acc[r] = 0.f;
    float bias = b[col];
    for (int kt = 0; kt < C; kt += 32) {
#pragma unroll
        for (int j = 0; j < 16; ++j) {
            int i = j * 256 + t, wc = i >> 5, kl = i & 31;
            Ws[kl][wc] = W[(size_t)wc * C + kt + kl];
        }
#pragma unroll
        for (int j = 0; j < 4; ++j) {
            int i = j * 256 + t, r = i >> 5, kl = i & 31;
            size_t gi = (size_t)(row0 + r) * C + kt + kl;
            ins[r][kl] = x0[gi] + m[gi];
        }
        __syncthreads();
#pragma unroll
        for (int kl = 0; kl < 32; ++kl) {
            float wv = Ws[kl][col];
#pragma unroll
            for (int r = 0; r < 16; ++r)
                acc[r] += ins[rg * 16 + r][kl] * wv;
        }
        __syncthreads();
    }
#pragma unroll
    for (int r = 0; r < 16; ++r)
        out[(size_t)(row0 + rg * 16 + r) * C + col] = acc[r] + bias;
}

extern "C" void kernel_launch(void* const* d_in, const int* in_sizes, int n_in,
                              void* d_out, int out_size, void* d_ws, size_t ws_size,
                              hipStream_t stream) {
    const float* x0 = (const float*)d_in[0];
    const int* nidx = (const int*)d_in[1];
    const int* eidx = (const int*)d_in[2];
    const float* W  = (const float*)d_in[3];
    const float* b  = (const float*)d_in[4];

    float* out0 = (float*)d_out;
    float* x1   = out0 + (size_t)N_NODES * C;
    int nnz = in_sizes[1];

    // ---- workspace layout (8B-aligned first) ----
    char* p = (char*)d_ws;
    uint64_t* pe = (uint64_t*)p; p += (size_t)nnz * sizeof(uint64_t);
    uint64_t* pn = (uint64_t*)p; p += (size_t)nnz * sizeof(uint64_t);
    int* e_list = (int*)p; p += (size_t)nnz * sizeof(int);
    int* n_list = (int*)p; p += (size_t)nnz * sizeof(int);
    int* ecnt   = (int*)p; p += (size_t)N_EDGES * sizeof(int);   // ecnt+ncnt contiguous
    int* ncnt   = (int*)p; p += (size_t)N_NODES * sizeof(int);
    int* eoff   = (int*)p; p += (size_t)(N_EDGES + 1) * sizeof(int);
    int* noff   = (int*)p; p += (size_t)(N_NODES + 1) * sizeof(int);
    int* Cecur  = (int*)p; p += (size_t)NB * sizeof(int);
    int* Cncur  = (int*)p; p += (size_t)NB * sizeof(int);
    size_t needed = (size_t)(p - (char*)d_ws);

    if (ws_size < needed) {
        // Fallback: atomic scatter path using ws only for m.
        float* m = (float*)d_ws;
        hipMemsetAsync(x1, 0, (size_t)N_EDGES * C * sizeof(float), stream);
        hipMemsetAsync(m,  0, (size_t)N_NODES * C * sizeof(float), stream);
        int blocks = (nnz + 7) / 8;
        scatter_rows<<<blocks, 256, 0, stream>>>((const float4*)x0, nidx, eidx, x1, nnz);
        scatter_rows<<<blocks, 256, 0, stream>>>((const float4*)x1, eidx, nidx, m, nnz);
        gin_gemm<<<N_NODES / 32, 256, 0, stream>>>(x0, m, W, b, out0);
        return;
    }

    // ---- CSR build (sort-based, no scattered 4B writes) ----
    hipMemsetAsync(ecnt, 0, (size_t)(N_EDGES + N_NODES) * sizeof(int), stream);
    hist_kernel<<<2048, 256, 0, stream>>>(nidx, eidx, ncnt, ecnt, nnz);
    scan_kernel<<<1, 1024, 0, stream>>>(ecnt, eoff, nullptr, N_EDGES);
    scan_kernel<<<1, 1024, 0, stream>>>(ncnt, noff, nullptr, N_NODES);
    init_cursors<<<1, 256, 0, stream>>>(eoff, noff, Cecur, Cncur);
    partition_kernel<<<(nnz + 4095) / 4096, 256, 0, stream>>>(
        nidx, eidx, Cecur, Cncur, pe, pn, nnz);
    bucket_scatter<<<NB, 256, 0, stream>>>(pe, eoff, e_list, 256, N_EDGES);
    bucket_scatter<<<NB, 256, 0, stream>>>(pn, noff, n_list, 512, N_NODES);

    // ---- step 1: x1[e] = sum_{n in e} x0[n] ----
    seg_sum<<<(N_EDGES * 64 + 255) / 256, 256, 0, stream>>>(
        (const float2*)x0, e_list, eoff, (float2*)x1, N_EDGES);

    // ---- steps 2+3 fused: out0 = (x0 + sum_{e ∋ n} x1[e]) @ W^T + b ----
    gin_fused<<<N_NODES / 32, 256, 0, stream>>>(
        (const float2*)x0, (const float2*)x1, n_list, noff, W, b, out0);
}

// Round 4
// 823.807 us; speedup vs baseline: 6.6842x; 1.2106x over previous
//
#include <hip/hip_runtime.h>
#include <stdint.h>

#define N_NODES 100000
#define N_EDGES 50000
#define C 128
#define NB 196        // coarse buckets: ceil(50000/256) == ceil(100000/512)
#define CAP 12288     // LDS staging entries per bucket (48KB)

// ---------------- exact histograms ----------------
__global__ __launch_bounds__(256) void hist_kernel(
    const int* __restrict__ nidx, const int* __restrict__ eidx,
    int* __restrict__ ncnt, int* __restrict__ ecnt, int nnz)
{
    for (int i = blockIdx.x * 256 + threadIdx.x; i < nnz; i += gridDim.x * 256) {
        atomicAdd(&ecnt[eidx[i]], 1);
        atomicAdd(&ncnt[nidx[i]], 1);
    }
}

// ---------------- single-block exclusive scan ----------------
__global__ __launch_bounds__(1024) void scan_kernel(
    const int* __restrict__ cnt, int* __restrict__ off,
    int* __restrict__ cur, int n)
{
    __shared__ int s[1024];
    int t = threadIdx.x;
    int K = (n + 1023) >> 10;
    int lo = t * K, hi = lo + K;
    if (lo > n) lo = n;
    if (hi > n) hi = n;
    int sum = 0;
    for (int i = lo; i < hi; ++i) sum += cnt[i];
    s[t] = sum;
    __syncthreads();
    for (int d = 1; d < 1024; d <<= 1) {
        int v = (t >= d) ? s[t - d] : 0;
        __syncthreads();
        s[t] += v;
        __syncthreads();
    }
    int run = s[t] - sum;
    for (int i = lo; i < hi; ++i) {
        off[i] = run;
        if (cur) cur[i] = run;
        run += cnt[i];
    }
    if (t == 1023) off[n] = s[1023];
}

// Coarse-bucket cursors are just exact offsets at bucket boundaries.
__global__ void init_cursors(const int* __restrict__ eoff, const int* __restrict__ noff,
                             int* __restrict__ Cecur, int* __restrict__ Cncur)
{
    int t = threadIdx.x;
    if (t < NB) {
        Cecur[t] = eoff[t * 256];
        Cncur[t] = noff[t * 512];
    }
}

// ---------------- phase B1: partition pairs into coarse buckets ----------------
__global__ __launch_bounds__(256) void partition_kernel(
    const int* __restrict__ nidx, const int* __restrict__ eidx,
    int* __restrict__ Cecur, int* __restrict__ Cncur,
    uint64_t* __restrict__ pe, uint64_t* __restrict__ pn, int nnz)
{
    __shared__ int he[NB], hn[NB], be[NB], bn[NB];
    int t = threadIdx.x;
    int chunk0 = blockIdx.x * 4096;
    for (int k = t; k < NB; k += 256) { he[k] = 0; hn[k] = 0; }
    __syncthreads();
#pragma unroll 4
    for (int j = 0; j < 16; ++j) {
        int i = chunk0 + j * 256 + t;
        if (i < nnz) {
            atomicAdd(&he[eidx[i] >> 8], 1);
            atomicAdd(&hn[nidx[i] >> 9], 1);
        }
    }
    __syncthreads();
    for (int k = t; k < NB; k += 256) {
        be[k] = atomicAdd(&Cecur[k], he[k]);
        bn[k] = atomicAdd(&Cncur[k], hn[k]);
        he[k] = 0; hn[k] = 0;
    }
    __syncthreads();
#pragma unroll 4
    for (int j = 0; j < 16; ++j) {
        int i = chunk0 + j * 256 + t;
        if (i < nnz) {
            int e = eidx[i], n = nidx[i];
            int re = atomicAdd(&he[e >> 8], 1);
            pe[be[e >> 8] + re] = ((uint64_t)e << 32) | (uint32_t)n;
            int rn = atomicAdd(&hn[n >> 9], 1);
            pn[bn[n >> 9] + rn] = ((uint64_t)n << 32) | (uint32_t)e;
        }
    }
}

// ---------------- phase B2: within-bucket exact scatter via LDS ----------------
__global__ __launch_bounds__(256) void bucket_scatter(
    const uint64_t* __restrict__ pairs, const int* __restrict__ off,
    int* __restrict__ out, int kpb, int nkeys)
{
    __shared__ int cursor[512];
    __shared__ int vals[CAP];
    int t = threadIdx.x;
    int key0 = blockIdx.x * kpb;
    int key1 = key0 + kpb; if (key1 > nkeys) key1 = nkeys;
    int start = off[key0], end = off[key1];
    for (int k = t; k < key1 - key0; k += 256) cursor[k] = off[key0 + k] - start;
    __syncthreads();
    for (int i = start + t; i < end; i += 256) {
        uint64_t p = pairs[i];
        int key = (int)(p >> 32);
        int val = (int)(uint32_t)p;
        int pos = atomicAdd(&cursor[key - key0], 1);
        if (pos < CAP) vals[pos] = val;
        else out[start + pos] = val;
    }
    __syncthreads();
    int sz = end - start; if (sz > CAP) sz = CAP;
    for (int j = t; j < sz; j += 256) out[start + j] = vals[j];
}

// ---------------- 8-deep MLP gather-sum of rows [s0,s1) ----------------
__device__ __forceinline__ float2 gather_row_sum(
    const float2* __restrict__ src, const int* __restrict__ list,
    int s0, int s1, int lane)
{
    float2 a0{0.f,0.f}, a1{0.f,0.f}, a2{0.f,0.f}, a3{0.f,0.f};
    float2 a4{0.f,0.f}, a5{0.f,0.f}, a6{0.f,0.f}, a7{0.f,0.f};
    for (int base = s0; base < s1; base += 64) {
        int cnt = s1 - base; if (cnt > 64) cnt = 64;
        int my = (lane < cnt) ? list[base + lane] : 0;
        int j = 0;
        for (; j + 8 <= cnt; j += 8) {
            int g0 = __shfl(my, j+0), g1 = __shfl(my, j+1);
            int g2 = __shfl(my, j+2), g3 = __shfl(my, j+3);
            int g4 = __shfl(my, j+4), g5 = __shfl(my, j+5);
            int g6 = __shfl(my, j+6), g7 = __shfl(my, j+7);
            float2 v0 = src[(size_t)g0 * 64 + lane];
            float2 v1 = src[(size_t)g1 * 64 + lane];
            float2 v2 = src[(size_t)g2 * 64 + lane];
            float2 v3 = src[(size_t)g3 * 64 + lane];
            float2 v4 = src[(size_t)g4 * 64 + lane];
            float2 v5 = src[(size_t)g5 * 64 + lane];
            float2 v6 = src[(size_t)g6 * 64 + lane];
            float2 v7 = src[(size_t)g7 * 64 + lane];
            a0.x += v0.x; a0.y += v0.y;  a1.x += v1.x; a1.y += v1.y;
            a2.x += v2.x; a2.y += v2.y;  a3.x += v3.x; a3.y += v3.y;
            a4.x += v4.x; a4.y += v4.y;  a5.x += v5.x; a5.y += v5.y;
            a6.x += v6.x; a6.y += v6.y;  a7.x += v7.x; a7.y += v7.y;
        }
        for (; j < cnt; ++j) {
            int g = __shfl(my, j);
            float2 v = src[(size_t)g * 64 + lane];
            a0.x += v.x; a0.y += v.y;
        }
    }
    a0.x += a1.x; a0.y += a1.y;  a2.x += a3.x; a2.y += a3.y;
    a4.x += a5.x; a4.y += a5.y;  a6.x += a7.x; a6.y += a7.y;
    a0.x += a2.x; a0.y += a2.y;  a4.x += a6.x; a4.y += a6.y;
    a0.x += a4.x; a0.y += a4.y;
    return a0;
}

// ---------------- segment sum: one wave per output row ----------------
__global__ __launch_bounds__(256) void seg_sum(
    const float2* __restrict__ src, const int* __restrict__ list,
    const int* __restrict__ off, float2* __restrict__ dst, int nseg)
{
    int wid  = (blockIdx.x * 256 + threadIdx.x) >> 6;
    int lane = threadIdx.x & 63;
    if (wid >= nseg) return;
    float2 acc = gather_row_sum(src, list, off[wid], off[wid + 1], lane);
    dst[(size_t)wid * 64 + lane] = acc;
}

// ---------------- fused: m-gather + GIN GEMM ----------------
__global__ __launch_bounds__(256) void gin_fused(
    const float2* __restrict__ x0, const float2* __restrict__ x1,
    const int* __restrict__ n_list, const int* __restrict__ noff,
    const float* __restrict__ W, const float* __restrict__ b,
    float* __restrict__ out)
{
    __shared__ float ins[32][130];
    __shared__ float Ws[32][129];
    int t = threadIdx.x;
    int lane = t & 63, w = t >> 6;      // 4 waves
    int row0 = blockIdx.x * 32;

    for (int r = w * 8; r < w * 8 + 8; ++r) {
        int node = row0 + r;
        float2 base = x0[(size_t)node * 64 + lane];
        float2 g = gather_row_sum(x1, n_list, noff[node], noff[node + 1], lane);
        ins[r][lane * 2]     = base.x + g.x;
        ins[r][lane * 2 + 1] = base.y + g.y;
    }
    __syncthreads();

    int col = t & 127, rg = t >> 7;
    float acc[16];
#pragma unroll
    for (int r = 0; r < 16; ++r) acc[r] = 0.f;
    float bias = b[col];
    for (int kt = 0; kt < C; kt += 32) {
#pragma unroll
        for (int j = 0; j < 16; ++j) {
            int i = j * 256 + t, wc = i >> 5, kl = i & 31;
            Ws[kl][wc] = W[(size_t)wc * C + kt + kl];
        }
        __syncthreads();
#pragma unroll
        for (int kl = 0; kl < 32; ++kl) {
            float wv = Ws[kl][col];
#pragma unroll
            for (int r = 0; r < 16; ++r)
                acc[r] += ins[rg * 16 + r][kt + kl] * wv;
        }
        __syncthreads();
    }
#pragma unroll
    for (int r = 0; r < 16; ++r)
        out[(size_t)(row0 + rg * 16 + r) * C + col] = acc[r] + bias;
}

// ---------------- fallback atomic path ----------------
__global__ __launch_bounds__(256) void scatter_rows(
    const float4* __restrict__ src, const int* __restrict__ gather_idx,
    const int* __restrict__ scatter_idx, float* __restrict__ dst, int nnz)
{
    int gid = blockIdx.x * 256 + threadIdx.x;
    int row = gid >> 5, lane = gid & 31;
    if (row >= nnz) return;
    float4 v = src[(size_t)gather_idx[row] * 32 + lane];
    float* d = dst + (size_t)scatter_idx[row] * C + lane * 4;
    atomicAdd(d + 0, v.x); atomicAdd(d + 1, v.y);
    atomicAdd(d + 2, v.z); atomicAdd(d + 3, v.w);
}

__global__ __launch_bounds__(256) void gin_gemm(
    const float* __restrict__ x0, const float* __restrict__ m,
    const float* __restrict__ W, const float* __restrict__ b,
    float* __restrict__ out)
{
    __shared__ float Ws[32][129];
    __shared__ float ins[32][33];
    int t = threadIdx.x;
    int col = t & 127, rg = t >> 7;
    int row0 = blockIdx.x * 32;
    float acc[16];
#pragma unroll
    for (int r = 0; r < 16; ++r) acc[r] = 0.f;
    float bias = b[col];
    for (int kt = 0; kt < C; kt += 32) {
#pragma unroll
        for (int j = 0; j < 16; ++j) {
            int i = j * 256 + t, wc = i >> 5, kl = i & 31;
            Ws[kl][wc] = W[(size_t)wc * C + kt + kl];
        }
#pragma unroll
        for (int j = 0; j < 4; ++j) {
            int i = j * 256 + t, r = i >> 5, kl = i & 31;
            size_t gi = (size_t)(row0 + r) * C + kt + kl;
            ins[r][kl] = x0[gi] + m[gi];
        }
        __syncthreads();
#pragma unroll
        for (int kl = 0; kl < 32; ++kl) {
            float wv = Ws[kl][col];
#pragma unroll
            for (int r = 0; r < 16; ++r)
                acc[r] += ins[rg * 16 + r][kl] * wv;
        }
        __syncthreads();
    }
#pragma unroll
    for (int r = 0; r < 16; ++r)
        out[(size_t)(row0 + rg * 16 + r) * C + col] = acc[r] + bias;
}

extern "C" void kernel_launch(void* const* d_in, const int* in_sizes, int n_in,
                              void* d_out, int out_size, void* d_ws, size_t ws_size,
                              hipStream_t stream) {
    const float* x0 = (const float*)d_in[0];
    const int* nidx = (const int*)d_in[1];
    const int* eidx = (const int*)d_in[2];
    const float* W  = (const float*)d_in[3];
    const float* b  = (const float*)d_in[4];

    float* out0 = (float*)d_out;
    float* x1   = out0 + (size_t)N_NODES * C;
    int nnz = in_sizes[1];

    // ---- workspace layout (8B-aligned first) ----
    char* p = (char*)d_ws;
    uint64_t* pe = (uint64_t*)p; p += (size_t)nnz * sizeof(uint64_t);
    uint64_t* pn = (uint64_t*)p; p += (size_t)nnz * sizeof(uint64_t);
    int* e_list = (int*)p; p += (size_t)nnz * sizeof(int);
    int* n_list = (int*)p; p += (size_t)nnz * sizeof(int);
    int* ecnt   = (int*)p; p += (size_t)N_EDGES * sizeof(int);
    int* ncnt   = (int*)p; p += (size_t)N_NODES * sizeof(int);
    int* eoff   = (int*)p; p += (size_t)(N_EDGES + 1) * sizeof(int);
    int* noff   = (int*)p; p += (size_t)(N_NODES + 1) * sizeof(int);
    int* Cecur  = (int*)p; p += (size_t)NB * sizeof(int);
    int* Cncur  = (int*)p; p += (size_t)NB * sizeof(int);
    size_t needed = (size_t)(p - (char*)d_ws);

    if (ws_size < needed) {
        float* m = (float*)d_ws;
        hipMemsetAsync(x1, 0, (size_t)N_EDGES * C * sizeof(float), stream);
        hipMemsetAsync(m,  0, (size_t)N_NODES * C * sizeof(float), stream);
        int blocks = (nnz + 7) / 8;
        scatter_rows<<<blocks, 256, 0, stream>>>((const float4*)x0, nidx, eidx, x1, nnz);
        scatter_rows<<<blocks, 256, 0, stream>>>((const float4*)x1, eidx, nidx, m, nnz);
        gin_gemm<<<N_NODES / 32, 256, 0, stream>>>(x0, m, W, b, out0);
        return;
    }

    // ---- CSR build (sort-based, no scattered 4B writes) ----
    hipMemsetAsync(ecnt, 0, (size_t)(N_EDGES + N_NODES) * sizeof(int), stream);
    hist_kernel<<<2048, 256, 0, stream>>>(nidx, eidx, ncnt, ecnt, nnz);
    scan_kernel<<<1, 1024, 0, stream>>>(ecnt, eoff, nullptr, N_EDGES);
    scan_kernel<<<1, 1024, 0, stream>>>(ncnt, noff, nullptr, N_NODES);
    init_cursors<<<1, 256, 0, stream>>>(eoff, noff, Cecur, Cncur);
    partition_kernel<<<(nnz + 4095) / 4096, 256, 0, stream>>>(
        nidx, eidx, Cecur, Cncur, pe, pn, nnz);
    bucket_scatter<<<NB, 256, 0, stream>>>(pe, eoff, e_list, 256, N_EDGES);
    bucket_scatter<<<NB, 256, 0, stream>>>(pn, noff, n_list, 512, N_NODES);

    // ---- step 1: x1[e] = sum_{n in e} x0[n] ----
    seg_sum<<<(N_EDGES * 64 + 255) / 256, 256, 0, stream>>>(
        (const float2*)x0, e_list, eoff, (float2*)x1, N_EDGES);

    // ---- steps 2+3 fused: out0 = (x0 + sum_{e ∋ n} x1[e]) @ W^T + b ----
    gin_fused<<<N_NODES / 32, 256, 0, stream>>>(
        (const float2*)x0, (const float2*)x1, n_list, noff, W, b, out0);
}

// Round 5
// 607.831 us; speedup vs baseline: 9.0593x; 1.3553x over previous
//
#include <hip/hip_runtime.h>
#include <stdint.h>

#define N_NODES 100000
#define N_EDGES 50000
#define C 128
#define NB 196        // coarse buckets: ceil(50000/256) == ceil(100000/512)
#define CAP 12288     // LDS staging entries per bucket (48KB)

typedef short short8 __attribute__((ext_vector_type(8)));   // 8 bf16 (4 VGPRs)
typedef float f32x4  __attribute__((ext_vector_type(4)));

// ---------- bf16 helpers ----------
__device__ __forceinline__ unsigned int bf16rne(float f) {
    unsigned int u = __float_as_uint(f);
    return (u + 0x7FFFu + ((u >> 16) & 1u)) >> 16;    // finite inputs only
}
__device__ __forceinline__ unsigned int pk_bf16(float x, float y) {
    return (bf16rne(y) << 16) | bf16rne(x);
}
__device__ __forceinline__ float bf_lo(unsigned int u) { return __uint_as_float(u << 16); }
__device__ __forceinline__ float bf_hi(unsigned int u) { return __uint_as_float(u & 0xFFFF0000u); }

// ---------- fp32(x2) -> packed bf16 convert ----------
__global__ __launch_bounds__(256) void conv_bf16(
    const float2* __restrict__ in, unsigned int* __restrict__ outp, int n2)
{
    int i = blockIdx.x * 256 + threadIdx.x;
    if (i < n2) { float2 v = in[i]; outp[i] = pk_bf16(v.x, v.y); }
}

// ---------------- exact histograms ----------------
__global__ __launch_bounds__(256) void hist_kernel(
    const int* __restrict__ nidx, const int* __restrict__ eidx,
    int* __restrict__ ncnt, int* __restrict__ ecnt, int nnz)
{
    for (int i = blockIdx.x * 256 + threadIdx.x; i < nnz; i += gridDim.x * 256) {
        atomicAdd(&ecnt[eidx[i]], 1);
        atomicAdd(&ncnt[nidx[i]], 1);
    }
}

// ---------------- single-block exclusive scan ----------------
__global__ __launch_bounds__(1024) void scan_kernel(
    const int* __restrict__ cnt, int* __restrict__ off, int n)
{
    __shared__ int s[1024];
    int t = threadIdx.x;
    int K = (n + 1023) >> 10;
    int lo = t * K, hi = lo + K;
    if (lo > n) lo = n;
    if (hi > n) hi = n;
    int sum = 0;
    for (int i = lo; i < hi; ++i) sum += cnt[i];
    s[t] = sum;
    __syncthreads();
    for (int d = 1; d < 1024; d <<= 1) {
        int v = (t >= d) ? s[t - d] : 0;
        __syncthreads();
        s[t] += v;
        __syncthreads();
    }
    int run = s[t] - sum;
    for (int i = lo; i < hi; ++i) { off[i] = run; run += cnt[i]; }
    if (t == 1023) off[n] = s[1023];
}

__global__ void init_cursors(const int* __restrict__ eoff, const int* __restrict__ noff,
                             int* __restrict__ Cecur, int* __restrict__ Cncur)
{
    int t = threadIdx.x;
    if (t < NB) {
        Cecur[t] = eoff[t * 256];
        Cncur[t] = noff[t * 512];
    }
}

// ---------------- phase B1: partition pairs into coarse buckets ----------------
__global__ __launch_bounds__(256) void partition_kernel(
    const int* __restrict__ nidx, const int* __restrict__ eidx,
    int* __restrict__ Cecur, int* __restrict__ Cncur,
    uint64_t* __restrict__ pe, uint64_t* __restrict__ pn, int nnz)
{
    __shared__ int he[NB], hn[NB], be[NB], bn[NB];
    int t = threadIdx.x;
    int chunk0 = blockIdx.x * 4096;
    for (int k = t; k < NB; k += 256) { he[k] = 0; hn[k] = 0; }
    __syncthreads();
#pragma unroll 4
    for (int j = 0; j < 16; ++j) {
        int i = chunk0 + j * 256 + t;
        if (i < nnz) {
            atomicAdd(&he[eidx[i] >> 8], 1);
            atomicAdd(&hn[nidx[i] >> 9], 1);
        }
    }
    __syncthreads();
    for (int k = t; k < NB; k += 256) {
        be[k] = atomicAdd(&Cecur[k], he[k]);
        bn[k] = atomicAdd(&Cncur[k], hn[k]);
        he[k] = 0; hn[k] = 0;
    }
    __syncthreads();
#pragma unroll 4
    for (int j = 0; j < 16; ++j) {
        int i = chunk0 + j * 256 + t;
        if (i < nnz) {
            int e = eidx[i], n = nidx[i];
            int re = atomicAdd(&he[e >> 8], 1);
            pe[be[e >> 8] + re] = ((uint64_t)e << 32) | (uint32_t)n;
            int rn = atomicAdd(&hn[n >> 9], 1);
            pn[bn[n >> 9] + rn] = ((uint64_t)n << 32) | (uint32_t)e;
        }
    }
}

// ---------------- phase B2: within-bucket exact scatter via LDS ----------------
__global__ __launch_bounds__(256) void bucket_scatter(
    const uint64_t* __restrict__ pairs, const int* __restrict__ off,
    int* __restrict__ out, int kpb, int nkeys)
{
    __shared__ int cursor[512];
    __shared__ int vals[CAP];
    int t = threadIdx.x;
    int key0 = blockIdx.x * kpb;
    int key1 = key0 + kpb; if (key1 > nkeys) key1 = nkeys;
    int start = off[key0], end = off[key1];
    for (int k = t; k < key1 - key0; k += 256) cursor[k] = off[key0 + k] - start;
    __syncthreads();
    for (int i = start + t; i < end; i += 256) {
        uint64_t p = pairs[i];
        int key = (int)(p >> 32);
        int val = (int)(uint32_t)p;
        int pos = atomicAdd(&cursor[key - key0], 1);
        if (pos < CAP) vals[pos] = val;
        else out[start + pos] = val;
    }
    __syncthreads();
    int sz = end - start; if (sz > CAP) sz = CAP;
    for (int j = t; j < sz; j += 256) out[start + j] = vals[j];
}

// ---------------- 8-deep MLP gather-sum of packed-bf16 rows ----------------
// Row = 128 bf16 = 64 uints; lane owns channels (2*lane, 2*lane+1). fp32 accum.
__device__ __forceinline__ float2 gather_bf16_rows(
    const unsigned int* __restrict__ src, const int* __restrict__ list,
    int s0, int s1, int lane)
{
    float ax0=0,ay0=0,ax1=0,ay1=0,ax2=0,ay2=0,ax3=0,ay3=0;
    float ax4=0,ay4=0,ax5=0,ay5=0,ax6=0,ay6=0,ax7=0,ay7=0;
    for (int base = s0; base < s1; base += 64) {
        int cnt = s1 - base; if (cnt > 64) cnt = 64;
        int my = (lane < cnt) ? list[base + lane] : 0;
        int j = 0;
        for (; j + 8 <= cnt; j += 8) {
            int g0 = __shfl(my, j+0), g1 = __shfl(my, j+1);
            int g2 = __shfl(my, j+2), g3 = __shfl(my, j+3);
            int g4 = __shfl(my, j+4), g5 = __shfl(my, j+5);
            int g6 = __shfl(my, j+6), g7 = __shfl(my, j+7);
            unsigned int u0 = src[(size_t)g0 * 64 + lane];
            unsigned int u1 = src[(size_t)g1 * 64 + lane];
            unsigned int u2 = src[(size_t)g2 * 64 + lane];
            unsigned int u3 = src[(size_t)g3 * 64 + lane];
            unsigned int u4 = src[(size_t)g4 * 64 + lane];
            unsigned int u5 = src[(size_t)g5 * 64 + lane];
            unsigned int u6 = src[(size_t)g6 * 64 + lane];
            unsigned int u7 = src[(size_t)g7 * 64 + lane];
            ax0 += bf_lo(u0); ay0 += bf_hi(u0);  ax1 += bf_lo(u1); ay1 += bf_hi(u1);
            ax2 += bf_lo(u2); ay2 += bf_hi(u2);  ax3 += bf_lo(u3); ay3 += bf_hi(u3);
            ax4 += bf_lo(u4); ay4 += bf_hi(u4);  ax5 += bf_lo(u5); ay5 += bf_hi(u5);
            ax6 += bf_lo(u6); ay6 += bf_hi(u6);  ax7 += bf_lo(u7); ay7 += bf_hi(u7);
        }
        for (; j < cnt; ++j) {
            int g = __shfl(my, j);
            unsigned int u = src[(size_t)g * 64 + lane];
            ax0 += bf_lo(u); ay0 += bf_hi(u);
        }
    }
    ax0+=ax1; ay0+=ay1; ax2+=ax3; ay2+=ay3; ax4+=ax5; ay4+=ay5; ax6+=ax7; ay6+=ay7;
    ax0+=ax2; ay0+=ay2; ax4+=ax6; ay4+=ay6;
    ax0+=ax4; ay0+=ay4;
    return make_float2(ax0, ay0);
}

// ---------------- step 1: x1[e] = sum_{n in e} x0[n] (+ bf16 copy) ----------------
__global__ __launch_bounds__(256) void seg_sum(
    const unsigned int* __restrict__ x0h, const int* __restrict__ list,
    const int* __restrict__ off, float2* __restrict__ x1,
    unsigned int* __restrict__ x1h, int nseg)
{
    int wid  = (blockIdx.x * 256 + threadIdx.x) >> 6;
    int lane = threadIdx.x & 63;
    if (wid >= nseg) return;
    float2 acc = gather_bf16_rows(x0h, list, off[wid], off[wid + 1], lane);
    x1 [(size_t)wid * 64 + lane] = acc;
    x1h[(size_t)wid * 64 + lane] = pk_bf16(acc.x, acc.y);
}

// ---------------- steps 2+3 fused: gather + MFMA GEMM ----------------
// Block = 32 nodes x 128 cols, 4 waves.
__global__ __launch_bounds__(256) void gin_fused(
    const float2* __restrict__ x0, const unsigned int* __restrict__ x1h,
    const int* __restrict__ n_list, const int* __restrict__ noff,
    const unsigned short* __restrict__ Wh, const float* __restrict__ b,
    float* __restrict__ out)
{
    __shared__ __align__(16) unsigned short ins[32][136];  // bf16, +16B pad/row
    int t = threadIdx.x;
    int lane = t & 63, w = t >> 6;
    int row0 = blockIdx.x * 32;

    // Phase 1: gather-sum x1 rows (bf16) + x0 (fp32) -> ins (bf16)
    for (int r = w * 8; r < w * 8 + 8; ++r) {
        int node = row0 + r;
        float2 base = x0[(size_t)node * 64 + lane];
        float2 g = gather_bf16_rows(x1h, n_list, noff[node], noff[node + 1], lane);
        *(unsigned int*)&ins[r][lane * 2] = pk_bf16(base.x + g.x, base.y + g.y);
    }
    __syncthreads();

    // Phase 2: out[32x128] = ins @ Wh^T + b via mfma_f32_16x16x32_bf16
    int mt  = w & 1;            // M-tile (16 rows)
    int ntb = (w >> 1) * 4;     // first of 4 N-tiles
    int l15  = lane & 15;
    int koff = (lane >> 4) * 8; // 8 contiguous k per lane
    int arow = mt * 16 + l15;

    f32x4 acc0 = {0,0,0,0}, acc1 = {0,0,0,0}, acc2 = {0,0,0,0}, acc3 = {0,0,0,0};
#pragma unroll
    for (int kt = 0; kt < C; kt += 32) {
        short8 a = *(const short8*)&ins[arow][kt + koff];
        short8 b0 = *(const short8*)&Wh[(size_t)((ntb + 0) * 16 + l15) * C + kt + koff];
        short8 b1 = *(const short8*)&Wh[(size_t)((ntb + 1) * 16 + l15) * C + kt + koff];
        short8 b2 = *(const short8*)&Wh[(size_t)((ntb + 2) * 16 + l15) * C + kt + koff];
        short8 b3 = *(const short8*)&Wh[(size_t)((ntb + 3) * 16 + l15) * C + kt + koff];
        acc0 = __builtin_amdgcn_mfma_f32_16x16x32_bf16(a, b0, acc0, 0, 0, 0);
        acc1 = __builtin_amdgcn_mfma_f32_16x16x32_bf16(a, b1, acc1, 0, 0, 0);
        acc2 = __builtin_amdgcn_mfma_f32_16x16x32_bf16(a, b2, acc2, 0, 0, 0);
        acc3 = __builtin_amdgcn_mfma_f32_16x16x32_bf16(a, b3, acc3, 0, 0, 0);
    }

    // Epilogue: D layout col=lane&15, row=(lane>>4)*4+j
    int drow = row0 + mt * 16 + (lane >> 4) * 4;
#pragma unroll
    for (int n = 0; n < 4; ++n) {
        f32x4 accv = (n == 0) ? acc0 : (n == 1) ? acc1 : (n == 2) ? acc2 : acc3;
        int colg = (ntb + n) * 16 + l15;
        float bias = b[colg];
#pragma unroll
        for (int j = 0; j < 4; ++j)
            out[(size_t)(drow + j) * C + colg] = accv[j] + bias;
    }
}

// ---------------- fallback atomic path ----------------
__global__ __launch_bounds__(256) void scatter_rows(
    const float4* __restrict__ src, const int* __restrict__ gather_idx,
    const int* __restrict__ scatter_idx, float* __restrict__ dst, int nnz)
{
    int gid = blockIdx.x * 256 + threadIdx.x;
    int row = gid >> 5, lane = gid & 31;
    if (row >= nnz) return;
    float4 v = src[(size_t)gather_idx[row] * 32 + lane];
    float* d = dst + (size_t)scatter_idx[row] * C + lane * 4;
    atomicAdd(d + 0, v.x); atomicAdd(d + 1, v.y);
    atomicAdd(d + 2, v.z); atomicAdd(d + 3, v.w);
}

__global__ __launch_bounds__(256) void gin_gemm(
    const float* __restrict__ x0, const float* __restrict__ m,
    const float* __restrict__ W, const float* __restrict__ b,
    float* __restrict__ out)
{
    __shared__ float Ws[32][129];
    __shared__ float insf[32][33];
    int t = threadIdx.x;
    int col = t & 127, rg = t >> 7;
    int row0 = blockIdx.x * 32;
    float acc[16];
#pragma unroll
    for (int r = 0; r < 16; ++r) acc[r] = 0.f;
    float bias = b[col];
    for (int kt = 0; kt < C; kt += 32) {
#pragma unroll
        for (int j = 0; j < 16; ++j) {
            int i = j * 256 + t, wc = i >> 5, kl = i & 31;
            Ws[kl][wc] = W[(size_t)wc * C + kt + kl];
        }
#pragma unroll
        for (int j = 0; j < 4; ++j) {
            int i = j * 256 + t, r = i >> 5, kl = i & 31;
            size_t gi = (size_t)(row0 + r) * C + kt + kl;
            insf[r][kl] = x0[gi] + m[gi];
        }
        __syncthreads();
#pragma unroll
        for (int kl = 0; kl < 32; ++kl) {
            float wv = Ws[kl][col];
#pragma unroll
            for (int r = 0; r < 16; ++r)
                acc[r] += insf[rg * 16 + r][kl] * wv;
        }
        __syncthreads();
    }
#pragma unroll
    for (int r = 0; r < 16; ++r)
        out[(size_t)(row0 + rg * 16 + r) * C + col] = acc[r] + bias;
}

extern "C" void kernel_launch(void* const* d_in, const int* in_sizes, int n_in,
                              void* d_out, int out_size, void* d_ws, size_t ws_size,
                              hipStream_t stream) {
    const float* x0 = (const float*)d_in[0];
    const int* nidx = (const int*)d_in[1];
    const int* eidx = (const int*)d_in[2];
    const float* W  = (const float*)d_in[3];
    const float* b  = (const float*)d_in[4];

    float* out0 = (float*)d_out;
    float* x1   = out0 + (size_t)N_NODES * C;
    int nnz = in_sizes[1];

    // ---- workspace layout, each region 64B-aligned ----
    auto align64 = [](char* q) {
        return (char*)(((uintptr_t)q + 63) & ~(uintptr_t)63);
    };
    char* p = (char*)d_ws;
    uint64_t* pe = (uint64_t*)p;                       // pairs region, reused as x0h
    uint64_t* pn = pe + nnz;
    unsigned int* x0h = (unsigned int*)pe;             // N_NODES*64 uints = 2*nnz*8 bytes
    p = align64((char*)(pn + nnz));
    int* e_list = (int*)p; p = align64(p + (size_t)nnz * 4);
    int* n_list = (int*)p; p = align64(p + (size_t)nnz * 4);
    int* ecnt   = (int*)p;                              // ecnt+ncnt contiguous (one memset)
    int* ncnt   = ecnt + N_EDGES;
    p = align64((char*)(ncnt + N_NODES));
    int* eoff   = (int*)p; p = align64(p + (size_t)(N_EDGES + 1) * 4);
    int* noff   = (int*)p; p = align64(p + (size_t)(N_NODES + 1) * 4);
    int* Cecur  = (int*)p; p = align64(p + NB * 4);
    int* Cncur  = (int*)p; p = align64(p + NB * 4);
    unsigned int* x1h = (unsigned int*)p; p = align64(p + (size_t)N_EDGES * 64 * 4);
    unsigned int* Whu = (unsigned int*)p; p = align64(p + (size_t)C * C / 2 * 4);
    size_t needed = (size_t)(p - (char*)d_ws);

    if (ws_size < needed) {
        float* m = (float*)d_ws;
        hipMemsetAsync(x1, 0, (size_t)N_EDGES * C * sizeof(float), stream);
        hipMemsetAsync(m,  0, (size_t)N_NODES * C * sizeof(float), stream);
        int blocks = (nnz + 7) / 8;
        scatter_rows<<<blocks, 256, 0, stream>>>((const float4*)x0, nidx, eidx, x1, nnz);
        scatter_rows<<<blocks, 256, 0, stream>>>((const float4*)x1, eidx, nidx, m, nnz);
        gin_gemm<<<N_NODES / 32, 256, 0, stream>>>(x0, m, W, b, out0);
        return;
    }

    // ---- CSR build (sort-based) ----
    hipMemsetAsync(ecnt, 0, (size_t)(N_EDGES + N_NODES) * sizeof(int), stream);
    hist_kernel<<<2048, 256, 0, stream>>>(nidx, eidx, ncnt, ecnt, nnz);
    scan_kernel<<<1, 1024, 0, stream>>>(ecnt, eoff, N_EDGES);
    scan_kernel<<<1, 1024, 0, stream>>>(ncnt, noff, N_NODES);
    init_cursors<<<1, 256, 0, stream>>>(eoff, noff, Cecur, Cncur);
    partition_kernel<<<(nnz + 4095) / 4096, 256, 0, stream>>>(
        nidx, eidx, Cecur, Cncur, pe, pn, nnz);
    bucket_scatter<<<NB, 256, 0, stream>>>(pe, eoff, e_list, 256, N_EDGES);
    bucket_scatter<<<NB, 256, 0, stream>>>(pn, noff, n_list, 512, N_NODES);

    // ---- bf16 copies (x0h overwrites pairs region AFTER scatters consumed it) ----
    conv_bf16<<<(N_NODES * 64 + 255) / 256, 256, 0, stream>>>(
        (const float2*)x0, x0h, N_NODES * 64);
    conv_bf16<<<(C * C / 2 + 255) / 256, 256, 0, stream>>>(
        (const float2*)W, Whu, C * C / 2);

    // ---- step 1: x1 (fp32 out) + x1h (bf16) ----
    seg_sum<<<(N_EDGES * 64 + 255) / 256, 256, 0, stream>>>(
        x0h, e_list, eoff, (float2*)x1, x1h, N_EDGES);

    // ---- steps 2+3 fused ----
    gin_fused<<<N_NODES / 32, 256, 0, stream>>>(
        (const float2*)x0, x1h, n_list, noff,
        (const unsigned short*)Whu, b, out0);
}

// Round 6
// 388.120 us; speedup vs baseline: 14.1877x; 1.5661x over previous
//
#include <hip/hip_runtime.h>
#include <stdint.h>

#define N_NODES 100000
#define N_EDGES 50000
#define C 128
#define NB 196        // coarse buckets: ceil(50000/256) == ceil(100000/512)
#define CAP 12288     // LDS staging entries per bucket (48KB)
#define NCOMB (N_EDGES + N_NODES)       // 150000 combined counters
#define SCAN_CHUNK 2048
#define SCAN_BLKS ((NCOMB + SCAN_CHUNK - 1) / SCAN_CHUNK)   // 74

typedef short short8 __attribute__((ext_vector_type(8)));   // 8 bf16 (4 VGPRs)
typedef float f32x4  __attribute__((ext_vector_type(4)));

// ---------- bf16 helpers ----------
__device__ __forceinline__ unsigned int bf16rne(float f) {
    unsigned int u = __float_as_uint(f);
    return (u + 0x7FFFu + ((u >> 16) & 1u)) >> 16;    // finite inputs only
}
__device__ __forceinline__ unsigned int pk_bf16(float x, float y) {
    return (bf16rne(y) << 16) | bf16rne(x);
}
__device__ __forceinline__ float bf_lo(unsigned int u) { return __uint_as_float(u << 16); }
__device__ __forceinline__ float bf_hi(unsigned int u) { return __uint_as_float(u & 0xFFFF0000u); }

// ---------- fp32(x2) -> packed bf16 convert ----------
__global__ __launch_bounds__(256) void conv_bf16(
    const float2* __restrict__ in, unsigned int* __restrict__ outp, int n2)
{
    int i = blockIdx.x * 256 + threadIdx.x;
    if (i < n2) { float2 v = in[i]; outp[i] = pk_bf16(v.x, v.y); }
}

// ---------------- exact histograms ----------------
__global__ __launch_bounds__(256) void hist_kernel(
    const int* __restrict__ nidx, const int* __restrict__ eidx,
    int* __restrict__ ncnt, int* __restrict__ ecnt, int nnz)
{
    for (int i = blockIdx.x * 256 + threadIdx.x; i < nnz; i += gridDim.x * 256) {
        atomicAdd(&ecnt[eidx[i]], 1);
        atomicAdd(&ncnt[nidx[i]], 1);
    }
}

// ---------------- grid-parallel scan over combined ecnt||ncnt ----------------
__global__ __launch_bounds__(256) void scan_partial(
    const int* __restrict__ cnt, int* __restrict__ partial)
{
    __shared__ int s[256];
    int t = threadIdx.x;
    int base = blockIdx.x * SCAN_CHUNK;
    int sum = 0;
    for (int i = t; i < SCAN_CHUNK; i += 256) {
        int idx = base + i;
        if (idx < NCOMB) sum += cnt[idx];
    }
    s[t] = sum; __syncthreads();
    for (int d = 128; d > 0; d >>= 1) {
        if (t < d) s[t] += s[t + d];
        __syncthreads();
    }
    if (t == 0) partial[blockIdx.x] = s[0];
}

__global__ __launch_bounds__(128) void scan_partials(int* __restrict__ partial)
{
    __shared__ int s[128];
    int t = threadIdx.x;
    int v = (t < SCAN_BLKS) ? partial[t] : 0;
    s[t] = v; __syncthreads();
    for (int d = 1; d < 128; d <<= 1) {
        int u = (t >= d) ? s[t - d] : 0;
        __syncthreads();
        s[t] += u;
        __syncthreads();
    }
    if (t < SCAN_BLKS) partial[t] = s[t] - v;   // exclusive prefix
}

// Writes eoff[0..N_EDGES] and noff[0..N_NODES] (noff rebased by -nnz).
__global__ __launch_bounds__(256) void scan_final(
    const int* __restrict__ cnt, const int* __restrict__ partial,
    int* __restrict__ eoff, int* __restrict__ noff, int nnz)
{
    __shared__ int s[256];
    int t = threadIdx.x;
    int base = blockIdx.x * SCAN_CHUNK + t * 8;
    int v[8]; int sum = 0;
#pragma unroll
    for (int j = 0; j < 8; ++j) {
        int idx = base + j;
        v[j] = (idx < NCOMB) ? cnt[idx] : 0;
        sum += v[j];
    }
    s[t] = sum; __syncthreads();
    for (int d = 1; d < 256; d <<= 1) {
        int u = (t >= d) ? s[t - d] : 0;
        __syncthreads();
        s[t] += u;
        __syncthreads();
    }
    int run = partial[blockIdx.x] + (s[t] - sum);
#pragma unroll
    for (int j = 0; j < 8; ++j) {
        int idx = base + j;
        if (idx < NCOMB) {
            if (idx < N_EDGES) eoff[idx] = run;
            else               noff[idx - N_EDGES] = run - nnz;
            run += v[j];
        }
    }
    if (blockIdx.x == 0 && t == 0) { eoff[N_EDGES] = nnz; noff[N_NODES] = nnz; }
}

__global__ void init_cursors(const int* __restrict__ eoff, const int* __restrict__ noff,
                             int* __restrict__ Cecur, int* __restrict__ Cncur)
{
    int t = threadIdx.x;
    if (t < NB) {
        Cecur[t] = eoff[t * 256];
        Cncur[t] = noff[t * 512];
    }
}

// ---------------- phase B1: partition pairs into coarse buckets ----------------
__global__ __launch_bounds__(256) void partition_kernel(
    const int* __restrict__ nidx, const int* __restrict__ eidx,
    int* __restrict__ Cecur, int* __restrict__ Cncur,
    uint64_t* __restrict__ pe, uint64_t* __restrict__ pn, int nnz)
{
    __shared__ int he[NB], hn[NB], be[NB], bn[NB];
    int t = threadIdx.x;
    int chunk0 = blockIdx.x * 4096;
    for (int k = t; k < NB; k += 256) { he[k] = 0; hn[k] = 0; }
    __syncthreads();
#pragma unroll 4
    for (int j = 0; j < 16; ++j) {
        int i = chunk0 + j * 256 + t;
        if (i < nnz) {
            atomicAdd(&he[eidx[i] >> 8], 1);
            atomicAdd(&hn[nidx[i] >> 9], 1);
        }
    }
    __syncthreads();
    for (int k = t; k < NB; k += 256) {
        be[k] = atomicAdd(&Cecur[k], he[k]);
        bn[k] = atomicAdd(&Cncur[k], hn[k]);
        he[k] = 0; hn[k] = 0;
    }
    __syncthreads();
#pragma unroll 4
    for (int j = 0; j < 16; ++j) {
        int i = chunk0 + j * 256 + t;
        if (i < nnz) {
            int e = eidx[i], n = nidx[i];
            int re = atomicAdd(&he[e >> 8], 1);
            pe[be[e >> 8] + re] = ((uint64_t)e << 32) | (uint32_t)n;
            int rn = atomicAdd(&hn[n >> 9], 1);
            pn[bn[n >> 9] + rn] = ((uint64_t)n << 32) | (uint32_t)e;
        }
    }
}

// ---------------- phase B2: within-bucket exact scatter via LDS ----------------
__global__ __launch_bounds__(256) void bucket_scatter(
    const uint64_t* __restrict__ pairs, const int* __restrict__ off,
    int* __restrict__ out, int kpb, int nkeys)
{
    __shared__ int cursor[512];
    __shared__ int vals[CAP];
    int t = threadIdx.x;
    int key0 = blockIdx.x * kpb;
    int key1 = key0 + kpb; if (key1 > nkeys) key1 = nkeys;
    int start = off[key0], end = off[key1];
    for (int k = t; k < key1 - key0; k += 256) cursor[k] = off[key0 + k] - start;
    __syncthreads();
    for (int i = start + t; i < end; i += 256) {
        uint64_t p = pairs[i];
        int key = (int)(p >> 32);
        int val = (int)(uint32_t)p;
        int pos = atomicAdd(&cursor[key - key0], 1);
        if (pos < CAP) vals[pos] = val;
        else out[start + pos] = val;
    }
    __syncthreads();
    int sz = end - start; if (sz > CAP) sz = CAP;
    for (int j = t; j < sz; j += 256) out[start + j] = vals[j];
}

// ---------------- 8-deep MLP gather-sum of packed-bf16 rows ----------------
__device__ __forceinline__ float2 gather_bf16_rows(
    const unsigned int* __restrict__ src, const int* __restrict__ list,
    int s0, int s1, int lane)
{
    float ax0=0,ay0=0,ax1=0,ay1=0,ax2=0,ay2=0,ax3=0,ay3=0;
    float ax4=0,ay4=0,ax5=0,ay5=0,ax6=0,ay6=0,ax7=0,ay7=0;
    for (int base = s0; base < s1; base += 64) {
        int cnt = s1 - base; if (cnt > 64) cnt = 64;
        int my = (lane < cnt) ? list[base + lane] : 0;
        int j = 0;
        for (; j + 8 <= cnt; j += 8) {
            int g0 = __shfl(my, j+0), g1 = __shfl(my, j+1);
            int g2 = __shfl(my, j+2), g3 = __shfl(my, j+3);
            int g4 = __shfl(my, j+4), g5 = __shfl(my, j+5);
            int g6 = __shfl(my, j+6), g7 = __shfl(my, j+7);
            unsigned int u0 = src[(size_t)g0 * 64 + lane];
            unsigned int u1 = src[(size_t)g1 * 64 + lane];
            unsigned int u2 = src[(size_t)g2 * 64 + lane];
            unsigned int u3 = src[(size_t)g3 * 64 + lane];
            unsigned int u4 = src[(size_t)g4 * 64 + lane];
            unsigned int u5 = src[(size_t)g5 * 64 + lane];
            unsigned int u6 = src[(size_t)g6 * 64 + lane];
            unsigned int u7 = src[(size_t)g7 * 64 + lane];
            ax0 += bf_lo(u0); ay0 += bf_hi(u0);  ax1 += bf_lo(u1); ay1 += bf_hi(u1);
            ax2 += bf_lo(u2); ay2 += bf_hi(u2);  ax3 += bf_lo(u3); ay3 += bf_hi(u3);
            ax4 += bf_lo(u4); ay4 += bf_hi(u4);  ax5 += bf_lo(u5); ay5 += bf_hi(u5);
            ax6 += bf_lo(u6); ay6 += bf_hi(u6);  ax7 += bf_lo(u7); ay7 += bf_hi(u7);
        }
        for (; j < cnt; ++j) {
            int g = __shfl(my, j);
            unsigned int u = src[(size_t)g * 64 + lane];
            ax0 += bf_lo(u); ay0 += bf_hi(u);
        }
    }
    ax0+=ax1; ay0+=ay1; ax2+=ax3; ay2+=ay3; ax4+=ax5; ay4+=ay5; ax6+=ax7; ay6+=ay7;
    ax0+=ax2; ay0+=ay2; ax4+=ax6; ay4+=ay6;
    ax0+=ax4; ay0+=ay4;
    return make_float2(ax0, ay0);
}

// ---------------- step 1: x1[e] = sum_{n in e} x0[n] (+ bf16 copy) ----------------
__global__ __launch_bounds__(256) void seg_sum(
    const unsigned int* __restrict__ x0h, const int* __restrict__ list,
    const int* __restrict__ off, float2* __restrict__ x1,
    unsigned int* __restrict__ x1h, int nseg)
{
    int wid  = (blockIdx.x * 256 + threadIdx.x) >> 6;
    int lane = threadIdx.x & 63;
    if (wid >= nseg) return;
    float2 acc = gather_bf16_rows(x0h, list, off[wid], off[wid + 1], lane);
    x1 [(size_t)wid * 64 + lane] = acc;
    x1h[(size_t)wid * 64 + lane] = pk_bf16(acc.x, acc.y);
}

// ---------------- steps 2+3 fused: gather + MFMA GEMM ----------------
__global__ __launch_bounds__(256) void gin_fused(
    const float2* __restrict__ x0, const unsigned int* __restrict__ x1h,
    const int* __restrict__ n_list, const int* __restrict__ noff,
    const unsigned short* __restrict__ Wh, const float* __restrict__ b,
    float* __restrict__ out)
{
    __shared__ __align__(16) unsigned short ins[32][136];  // bf16, +16B pad/row
    int t = threadIdx.x;
    int lane = t & 63, w = t >> 6;
    int row0 = blockIdx.x * 32;

    for (int r = w * 8; r < w * 8 + 8; ++r) {
        int node = row0 + r;
        float2 base = x0[(size_t)node * 64 + lane];
        float2 g = gather_bf16_rows(x1h, n_list, noff[node], noff[node + 1], lane);
        *(unsigned int*)&ins[r][lane * 2] = pk_bf16(base.x + g.x, base.y + g.y);
    }
    __syncthreads();

    int mt  = w & 1;            // M-tile (16 rows)
    int ntb = (w >> 1) * 4;     // first of 4 N-tiles
    int l15  = lane & 15;
    int koff = (lane >> 4) * 8;
    int arow = mt * 16 + l15;

    f32x4 acc0 = {0,0,0,0}, acc1 = {0,0,0,0}, acc2 = {0,0,0,0}, acc3 = {0,0,0,0};
#pragma unroll
    for (int kt = 0; kt < C; kt += 32) {
        short8 a = *(const short8*)&ins[arow][kt + koff];
        short8 b0 = *(const short8*)&Wh[(size_t)((ntb + 0) * 16 + l15) * C + kt + koff];
        short8 b1 = *(const short8*)&Wh[(size_t)((ntb + 1) * 16 + l15) * C + kt + koff];
        short8 b2 = *(const short8*)&Wh[(size_t)((ntb + 2) * 16 + l15) * C + kt + koff];
        short8 b3 = *(const short8*)&Wh[(size_t)((ntb + 3) * 16 + l15) * C + kt + koff];
        acc0 = __builtin_amdgcn_mfma_f32_16x16x32_bf16(a, b0, acc0, 0, 0, 0);
        acc1 = __builtin_amdgcn_mfma_f32_16x16x32_bf16(a, b1, acc1, 0, 0, 0);
        acc2 = __builtin_amdgcn_mfma_f32_16x16x32_bf16(a, b2, acc2, 0, 0, 0);
        acc3 = __builtin_amdgcn_mfma_f32_16x16x32_bf16(a, b3, acc3, 0, 0, 0);
    }

    int drow = row0 + mt * 16 + (lane >> 4) * 4;
#pragma unroll
    for (int n = 0; n < 4; ++n) {
        f32x4 accv = (n == 0) ? acc0 : (n == 1) ? acc1 : (n == 2) ? acc2 : acc3;
        int colg = (ntb + n) * 16 + l15;
        float bias = b[colg];
#pragma unroll
        for (int j = 0; j < 4; ++j)
            out[(size_t)(drow + j) * C + colg] = accv[j] + bias;
    }
}

// ---------------- fallback atomic path ----------------
__global__ __launch_bounds__(256) void scatter_rows(
    const float4* __restrict__ src, const int* __restrict__ gather_idx,
    const int* __restrict__ scatter_idx, float* __restrict__ dst, int nnz)
{
    int gid = blockIdx.x * 256 + threadIdx.x;
    int row = gid >> 5, lane = gid & 31;
    if (row >= nnz) return;
    float4 v = src[(size_t)gather_idx[row] * 32 + lane];
    float* d = dst + (size_t)scatter_idx[row] * C + lane * 4;
    atomicAdd(d + 0, v.x); atomicAdd(d + 1, v.y);
    atomicAdd(d + 2, v.z); atomicAdd(d + 3, v.w);
}

__global__ __launch_bounds__(256) void gin_gemm(
    const float* __restrict__ x0, const float* __restrict__ m,
    const float* __restrict__ W, const float* __restrict__ b,
    float* __restrict__ out)
{
    __shared__ float Ws[32][129];
    __shared__ float insf[32][33];
    int t = threadIdx.x;
    int col = t & 127, rg = t >> 7;
    int row0 = blockIdx.x * 32;
    float acc[16];
#pragma unroll
    for (int r = 0; r < 16; ++r) acc[r] = 0.f;
    float bias = b[col];
    for (int kt = 0; kt < C; kt += 32) {
#pragma unroll
        for (int j = 0; j < 16; ++j) {
            int i = j * 256 + t, wc = i >> 5, kl = i & 31;
            Ws[kl][wc] = W[(size_t)wc * C + kt + kl];
        }
#pragma unroll
        for (int j = 0; j < 4; ++j) {
            int i = j * 256 + t, r = i >> 5, kl = i & 31;
            size_t gi = (size_t)(row0 + r) * C + kt + kl;
            insf[r][kl] = x0[gi] + m[gi];
        }
        __syncthreads();
#pragma unroll
        for (int kl = 0; kl < 32; ++kl) {
            float wv = Ws[kl][col];
#pragma unroll
            for (int r = 0; r < 16; ++r)
                acc[r] += insf[rg * 16 + r][kl] * wv;
        }
        __syncthreads();
    }
#pragma unroll
    for (int r = 0; r < 16; ++r)
        out[(size_t)(row0 + rg * 16 + r) * C + col] = acc[r] + bias;
}

extern "C" void kernel_launch(void* const* d_in, const int* in_sizes, int n_in,
                              void* d_out, int out_size, void* d_ws, size_t ws_size,
                              hipStream_t stream) {
    const float* x0 = (const float*)d_in[0];
    const int* nidx = (const int*)d_in[1];
    const int* eidx = (const int*)d_in[2];
    const float* W  = (const float*)d_in[3];
    const float* b  = (const float*)d_in[4];

    float* out0 = (float*)d_out;
    float* x1   = out0 + (size_t)N_NODES * C;
    int nnz = in_sizes[1];

    // ---- workspace layout, each region 64B-aligned ----
    auto align64 = [](char* q) {
        return (char*)(((uintptr_t)q + 63) & ~(uintptr_t)63);
    };
    char* p = (char*)d_ws;
    uint64_t* pe = (uint64_t*)p;                       // pairs region, reused as x0h
    uint64_t* pn = pe + nnz;
    unsigned int* x0h = (unsigned int*)pe;             // N_NODES*64 uints fits in pairs region
    p = align64((char*)(pn + nnz));
    int* e_list = (int*)p; p = align64(p + (size_t)nnz * 4);
    int* n_list = (int*)p; p = align64(p + (size_t)nnz * 4);
    int* ecnt   = (int*)p;                              // ecnt+ncnt contiguous (one memset, one scan)
    int* ncnt   = ecnt + N_EDGES;
    p = align64((char*)(ncnt + N_NODES));
    int* eoff   = (int*)p; p = align64(p + (size_t)(N_EDGES + 1) * 4);
    int* noff   = (int*)p; p = align64(p + (size_t)(N_NODES + 1) * 4);
    int* Cecur  = (int*)p; p = align64(p + NB * 4);
    int* Cncur  = (int*)p; p = align64(p + NB * 4);
    int* partials = (int*)p; p = align64(p + 128 * 4);
    unsigned int* x1h = (unsigned int*)p; p = align64(p + (size_t)N_EDGES * 64 * 4);
    unsigned int* Whu = (unsigned int*)p; p = align64(p + (size_t)C * C / 2 * 4);
    size_t needed = (size_t)(p - (char*)d_ws);

    if (ws_size < needed) {
        float* m = (float*)d_ws;
        hipMemsetAsync(x1, 0, (size_t)N_EDGES * C * sizeof(float), stream);
        hipMemsetAsync(m,  0, (size_t)N_NODES * C * sizeof(float), stream);
        int blocks = (nnz + 7) / 8;
        scatter_rows<<<blocks, 256, 0, stream>>>((const float4*)x0, nidx, eidx, x1, nnz);
        scatter_rows<<<blocks, 256, 0, stream>>>((const float4*)x1, eidx, nidx, m, nnz);
        gin_gemm<<<N_NODES / 32, 256, 0, stream>>>(x0, m, W, b, out0);
        return;
    }

    // ---- CSR build (sort-based) ----
    hipMemsetAsync(ecnt, 0, (size_t)NCOMB * sizeof(int), stream);
    hist_kernel<<<2048, 256, 0, stream>>>(nidx, eidx, ncnt, ecnt, nnz);
    // grid-parallel combined scan: ecnt||ncnt -> eoff, noff
    scan_partial<<<SCAN_BLKS, 256, 0, stream>>>(ecnt, partials);
    scan_partials<<<1, 128, 0, stream>>>(partials);
    scan_final<<<SCAN_BLKS, 256, 0, stream>>>(ecnt, partials, eoff, noff, nnz);
    init_cursors<<<1, 256, 0, stream>>>(eoff, noff, Cecur, Cncur);
    partition_kernel<<<(nnz + 4095) / 4096, 256, 0, stream>>>(
        nidx, eidx, Cecur, Cncur, pe, pn, nnz);
    bucket_scatter<<<NB, 256, 0, stream>>>(pe, eoff, e_list, 256, N_EDGES);
    bucket_scatter<<<NB, 256, 0, stream>>>(pn, noff, n_list, 512, N_NODES);

    // ---- bf16 copies (x0h overwrites pairs region AFTER scatters consumed it) ----
    conv_bf16<<<(N_NODES * 64 + 255) / 256, 256, 0, stream>>>(
        (const float2*)x0, x0h, N_NODES * 64);
    conv_bf16<<<(C * C / 2 + 255) / 256, 256, 0, stream>>>(
        (const float2*)W, Whu, C * C / 2);

    // ---- step 1: x1 (fp32 out) + x1h (bf16) ----
    seg_sum<<<(N_EDGES * 64 + 255) / 256, 256, 0, stream>>>(
        x0h, e_list, eoff, (float2*)x1, x1h, N_EDGES);

    // ---- steps 2+3 fused ----
    gin_fused<<<N_NODES / 32, 256, 0, stream>>>(
        (const float2*)x0, x1h, n_list, noff,
        (const unsigned short*)Whu, b, out0);
}

// Round 7
// 263.282 us; speedup vs baseline: 20.9149x; 1.4742x over previous
//
#include <hip/hip_runtime.h>
#include <stdint.h>

#define N_NODES 100000
#define N_EDGES 50000
#define C 128
#define NB 196        // coarse buckets: ceil(50000/256) == ceil(100000/512)
#define CAP 12288     // LDS staging entries per bucket (48KB)

typedef short short8 __attribute__((ext_vector_type(8)));   // 8 bf16 (4 VGPRs)
typedef float f32x4  __attribute__((ext_vector_type(4)));

// ---------- bf16 helpers ----------
__device__ __forceinline__ unsigned int bf16rne(float f) {
    unsigned int u = __float_as_uint(f);
    return (u + 0x7FFFu + ((u >> 16) & 1u)) >> 16;    // finite inputs only
}
__device__ __forceinline__ unsigned int pk_bf16(float x, float y) {
    return (bf16rne(y) << 16) | bf16rne(x);
}
__device__ __forceinline__ float bf_lo(unsigned int u) { return __uint_as_float(u << 16); }
__device__ __forceinline__ float bf_hi(unsigned int u) { return __uint_as_float(u & 0xFFFF0000u); }

// ---------- fp32(x2) -> packed bf16 convert ----------
__global__ __launch_bounds__(256) void conv_bf16(
    const float2* __restrict__ in, unsigned int* __restrict__ outp, int n2)
{
    int i = blockIdx.x * 256 + threadIdx.x;
    if (i < n2) { float2 v = in[i]; outp[i] = pk_bf16(v.x, v.y); }
}

// ---------------- coarse histogram (LDS-privatized) ----------------
__global__ __launch_bounds__(256) void coarse_hist(
    const int* __restrict__ nidx, const int* __restrict__ eidx,
    int* __restrict__ Ceh, int* __restrict__ Cnh, int nnz)
{
    __shared__ int he[NB], hn[NB];
    int t = threadIdx.x;
    int chunk0 = blockIdx.x * 4096;
    for (int k = t; k < NB; k += 256) { he[k] = 0; hn[k] = 0; }
    __syncthreads();
#pragma unroll 4
    for (int j = 0; j < 16; ++j) {
        int i = chunk0 + j * 256 + t;
        if (i < nnz) {
            atomicAdd(&he[eidx[i] >> 8], 1);
            atomicAdd(&hn[nidx[i] >> 9], 1);
        }
    }
    __syncthreads();
    for (int k = t; k < NB; k += 256) {
        if (he[k]) atomicAdd(&Ceh[k], he[k]);
        if (hn[k]) atomicAdd(&Cnh[k], hn[k]);
    }
}

// ---------------- tiny scan: coarse counts -> bucket base cursors ----------------
__global__ __launch_bounds__(256) void coarse_scan(
    const int* __restrict__ Ceh, const int* __restrict__ Cnh,
    int* __restrict__ Cecur, int* __restrict__ Cncur)
{
    __shared__ int s[256];
    int t = threadIdx.x;
    // e-side
    int v = (t < NB) ? Ceh[t] : 0;
    s[t] = v; __syncthreads();
    for (int d = 1; d < 256; d <<= 1) {
        int u = (t >= d) ? s[t - d] : 0;
        __syncthreads(); s[t] += u; __syncthreads();
    }
    if (t < NB) Cecur[t] = s[t] - v;
    __syncthreads();
    // n-side
    v = (t < NB) ? Cnh[t] : 0;
    s[t] = v; __syncthreads();
    for (int d = 1; d < 256; d <<= 1) {
        int u = (t >= d) ? s[t - d] : 0;
        __syncthreads(); s[t] += u; __syncthreads();
    }
    if (t < NB) Cncur[t] = s[t] - v;
}

// ---------------- phase B1: partition pairs into coarse buckets ----------------
__global__ __launch_bounds__(256) void partition_kernel(
    const int* __restrict__ nidx, const int* __restrict__ eidx,
    int* __restrict__ Cecur, int* __restrict__ Cncur,
    uint64_t* __restrict__ pe, uint64_t* __restrict__ pn, int nnz)
{
    __shared__ int he[NB], hn[NB], be[NB], bn[NB];
    int t = threadIdx.x;
    int chunk0 = blockIdx.x * 4096;
    for (int k = t; k < NB; k += 256) { he[k] = 0; hn[k] = 0; }
    __syncthreads();
#pragma unroll 4
    for (int j = 0; j < 16; ++j) {
        int i = chunk0 + j * 256 + t;
        if (i < nnz) {
            atomicAdd(&he[eidx[i] >> 8], 1);
            atomicAdd(&hn[nidx[i] >> 9], 1);
        }
    }
    __syncthreads();
    for (int k = t; k < NB; k += 256) {
        be[k] = atomicAdd(&Cecur[k], he[k]);
        bn[k] = atomicAdd(&Cncur[k], hn[k]);
        he[k] = 0; hn[k] = 0;
    }
    __syncthreads();
#pragma unroll 4
    for (int j = 0; j < 16; ++j) {
        int i = chunk0 + j * 256 + t;
        if (i < nnz) {
            int e = eidx[i], n = nidx[i];
            int re = atomicAdd(&he[e >> 8], 1);
            pe[be[e >> 8] + re] = ((uint64_t)e << 32) | (uint32_t)n;
            int rn = atomicAdd(&hn[n >> 9], 1);
            pn[bn[n >> 9] + rn] = ((uint64_t)n << 32) | (uint32_t)e;
        }
    }
}

// ---------------- phase B2: fine hist + scan + scatter, all in LDS ----------------
// After partition, Cecur[b] / Cncur[b] hold END offsets of bucket b.
// Grid = 2*NB: blocks [0,NB) do e-side, [NB,2NB) do n-side.
__global__ __launch_bounds__(256) void bucket_scatter_ex(
    const uint64_t* __restrict__ pe, const uint64_t* __restrict__ pn,
    const int* __restrict__ Cecur, const int* __restrict__ Cncur,
    int* __restrict__ e_list, int* __restrict__ n_list,
    int* __restrict__ eoff, int* __restrict__ noff)
{
    __shared__ int cnt[512], cur[512], s[256];
    __shared__ int vals[CAP];
    bool eside = blockIdx.x < NB;
    int b = eside ? blockIdx.x : blockIdx.x - NB;
    const uint64_t* pairs = eside ? pe : pn;
    const int* endarr     = eside ? Cecur : Cncur;
    int* out              = eside ? e_list : n_list;
    int* off              = eside ? eoff : noff;
    int kpb   = eside ? 256 : 512;
    int nkeys = eside ? N_EDGES : N_NODES;
    int key0 = b * kpb;
    int nk = nkeys - key0; if (nk > kpb) nk = kpb;
    if (nk <= 0) return;
    int start = (b == 0) ? 0 : endarr[b - 1];
    int end   = endarr[b];
    int t = threadIdx.x;

    for (int k = t; k < nk; k += 256) cnt[k] = 0;
    __syncthreads();
    // fine histogram
    for (int i = start + t; i < end; i += 256)
        atomicAdd(&cnt[(int)(pairs[i] >> 32) - key0], 1);
    __syncthreads();
    // exclusive scan (2 keys/thread), write fine offsets
    int k0 = 2 * t, k1 = 2 * t + 1;
    int c0 = (k0 < nk) ? cnt[k0] : 0;
    int c1 = (k1 < nk) ? cnt[k1] : 0;
    int local = c0 + c1;
    s[t] = local; __syncthreads();
    for (int d = 1; d < 256; d <<= 1) {
        int u = (t >= d) ? s[t - d] : 0;
        __syncthreads(); s[t] += u; __syncthreads();
    }
    int excl = s[t] - local;
    if (k0 < nk) { cur[k0] = excl;      off[key0 + k0] = start + excl; }
    if (k1 < nk) { cur[k1] = excl + c0; off[key0 + k1] = start + excl + c0; }
    if (b == NB - 1 && t == 0) off[nkeys] = end;
    __syncthreads();
    // rank-scatter into LDS, then coalesced write-out
    for (int i = start + t; i < end; i += 256) {
        uint64_t p = pairs[i];
        int key = (int)(p >> 32) - key0;
        int val = (int)(uint32_t)p;
        int pos = atomicAdd(&cur[key], 1);
        if (pos < CAP) vals[pos] = val;
        else out[start + pos] = val;
    }
    __syncthreads();
    int sz = end - start; if (sz > CAP) sz = CAP;
    for (int j = t; j < sz; j += 256) out[start + j] = vals[j];
}

// ---------------- 8-deep MLP gather-sum of packed-bf16 rows ----------------
__device__ __forceinline__ float2 gather_bf16_rows(
    const unsigned int* __restrict__ src, const int* __restrict__ list,
    int s0, int s1, int lane)
{
    float ax0=0,ay0=0,ax1=0,ay1=0,ax2=0,ay2=0,ax3=0,ay3=0;
    float ax4=0,ay4=0,ax5=0,ay5=0,ax6=0,ay6=0,ax7=0,ay7=0;
    for (int base = s0; base < s1; base += 64) {
        int cnt = s1 - base; if (cnt > 64) cnt = 64;
        int my = (lane < cnt) ? list[base + lane] : 0;
        int j = 0;
        for (; j + 8 <= cnt; j += 8) {
            int g0 = __shfl(my, j+0), g1 = __shfl(my, j+1);
            int g2 = __shfl(my, j+2), g3 = __shfl(my, j+3);
            int g4 = __shfl(my, j+4), g5 = __shfl(my, j+5);
            int g6 = __shfl(my, j+6), g7 = __shfl(my, j+7);
            unsigned int u0 = src[(size_t)g0 * 64 + lane];
            unsigned int u1 = src[(size_t)g1 * 64 + lane];
            unsigned int u2 = src[(size_t)g2 * 64 + lane];
            unsigned int u3 = src[(size_t)g3 * 64 + lane];
            unsigned int u4 = src[(size_t)g4 * 64 + lane];
            unsigned int u5 = src[(size_t)g5 * 64 + lane];
            unsigned int u6 = src[(size_t)g6 * 64 + lane];
            unsigned int u7 = src[(size_t)g7 * 64 + lane];
            ax0 += bf_lo(u0); ay0 += bf_hi(u0);  ax1 += bf_lo(u1); ay1 += bf_hi(u1);
            ax2 += bf_lo(u2); ay2 += bf_hi(u2);  ax3 += bf_lo(u3); ay3 += bf_hi(u3);
            ax4 += bf_lo(u4); ay4 += bf_hi(u4);  ax5 += bf_lo(u5); ay5 += bf_hi(u5);
            ax6 += bf_lo(u6); ay6 += bf_hi(u6);  ax7 += bf_lo(u7); ay7 += bf_hi(u7);
        }
        for (; j < cnt; ++j) {
            int g = __shfl(my, j);
            unsigned int u = src[(size_t)g * 64 + lane];
            ax0 += bf_lo(u); ay0 += bf_hi(u);
        }
    }
    ax0+=ax1; ay0+=ay1; ax2+=ax3; ay2+=ay3; ax4+=ax5; ay4+=ay5; ax6+=ax7; ay6+=ay7;
    ax0+=ax2; ay0+=ay2; ax4+=ax6; ay4+=ay6;
    ax0+=ax4; ay0+=ay4;
    return make_float2(ax0, ay0);
}

// ---------------- step 1: x1[e] = sum_{n in e} x0[n] (+ bf16 copy) ----------------
__global__ __launch_bounds__(256) void seg_sum(
    const unsigned int* __restrict__ x0h, const int* __restrict__ list,
    const int* __restrict__ off, float2* __restrict__ x1,
    unsigned int* __restrict__ x1h, int nseg)
{
    int wid  = (blockIdx.x * 256 + threadIdx.x) >> 6;
    int lane = threadIdx.x & 63;
    if (wid >= nseg) return;
    float2 acc = gather_bf16_rows(x0h, list, off[wid], off[wid + 1], lane);
    x1 [(size_t)wid * 64 + lane] = acc;
    x1h[(size_t)wid * 64 + lane] = pk_bf16(acc.x, acc.y);
}

// ---------------- steps 2+3 fused: gather + MFMA GEMM ----------------
__global__ __launch_bounds__(256) void gin_fused(
    const float2* __restrict__ x0, const unsigned int* __restrict__ x1h,
    const int* __restrict__ n_list, const int* __restrict__ noff,
    const unsigned short* __restrict__ Wh, const float* __restrict__ b,
    float* __restrict__ out)
{
    __shared__ __align__(16) unsigned short ins[32][136];  // bf16, +16B pad/row
    int t = threadIdx.x;
    int lane = t & 63, w = t >> 6;
    int row0 = blockIdx.x * 32;

    for (int r = w * 8; r < w * 8 + 8; ++r) {
        int node = row0 + r;
        float2 base = x0[(size_t)node * 64 + lane];
        float2 g = gather_bf16_rows(x1h, n_list, noff[node], noff[node + 1], lane);
        *(unsigned int*)&ins[r][lane * 2] = pk_bf16(base.x + g.x, base.y + g.y);
    }
    __syncthreads();

    int mt  = w & 1;            // M-tile (16 rows)
    int ntb = (w >> 1) * 4;     // first of 4 N-tiles
    int l15  = lane & 15;
    int koff = (lane >> 4) * 8;
    int arow = mt * 16 + l15;

    f32x4 acc0 = {0,0,0,0}, acc1 = {0,0,0,0}, acc2 = {0,0,0,0}, acc3 = {0,0,0,0};
#pragma unroll
    for (int kt = 0; kt < C; kt += 32) {
        short8 a = *(const short8*)&ins[arow][kt + koff];
        short8 b0 = *(const short8*)&Wh[(size_t)((ntb + 0) * 16 + l15) * C + kt + koff];
        short8 b1 = *(const short8*)&Wh[(size_t)((ntb + 1) * 16 + l15) * C + kt + koff];
        short8 b2 = *(const short8*)&Wh[(size_t)((ntb + 2) * 16 + l15) * C + kt + koff];
        short8 b3 = *(const short8*)&Wh[(size_t)((ntb + 3) * 16 + l15) * C + kt + koff];
        acc0 = __builtin_amdgcn_mfma_f32_16x16x32_bf16(a, b0, acc0, 0, 0, 0);
        acc1 = __builtin_amdgcn_mfma_f32_16x16x32_bf16(a, b1, acc1, 0, 0, 0);
        acc2 = __builtin_amdgcn_mfma_f32_16x16x32_bf16(a, b2, acc2, 0, 0, 0);
        acc3 = __builtin_amdgcn_mfma_f32_16x16x32_bf16(a, b3, acc3, 0, 0, 0);
    }

    int drow = row0 + mt * 16 + (lane >> 4) * 4;
#pragma unroll
    for (int n = 0; n < 4; ++n) {
        f32x4 accv = (n == 0) ? acc0 : (n == 1) ? acc1 : (n == 2) ? acc2 : acc3;
        int colg = (ntb + n) * 16 + l15;
        float bias = b[colg];
#pragma unroll
        for (int j = 0; j < 4; ++j)
            out[(size_t)(drow + j) * C + colg] = accv[j] + bias;
    }
}

// ---------------- fallback atomic path ----------------
__global__ __launch_bounds__(256) void scatter_rows(
    const float4* __restrict__ src, const int* __restrict__ gather_idx,
    const int* __restrict__ scatter_idx, float* __restrict__ dst, int nnz)
{
    int gid = blockIdx.x * 256 + threadIdx.x;
    int row = gid >> 5, lane = gid & 31;
    if (row >= nnz) return;
    float4 v = src[(size_t)gather_idx[row] * 32 + lane];
    float* d = dst + (size_t)scatter_idx[row] * C + lane * 4;
    atomicAdd(d + 0, v.x); atomicAdd(d + 1, v.y);
    atomicAdd(d + 2, v.z); atomicAdd(d + 3, v.w);
}

__global__ __launch_bounds__(256) void gin_gemm(
    const float* __restrict__ x0, const float* __restrict__ m,
    const float* __restrict__ W, const float* __restrict__ b,
    float* __restrict__ out)
{
    __shared__ float Ws[32][129];
    __shared__ float insf[32][33];
    int t = threadIdx.x;
    int col = t & 127, rg = t >> 7;
    int row0 = blockIdx.x * 32;
    float acc[16];
#pragma unroll
    for (int r = 0; r < 16; ++r) acc[r] = 0.f;
    float bias = b[col];
    for (int kt = 0; kt < C; kt += 32) {
#pragma unroll
        for (int j = 0; j < 16; ++j) {
            int i = j * 256 + t, wc = i >> 5, kl = i & 31;
            Ws[kl][wc] = W[(size_t)wc * C + kt + kl];
        }
#pragma unroll
        for (int j = 0; j < 4; ++j) {
            int i = j * 256 + t, r = i >> 5, kl = i & 31;
            size_t gi = (size_t)(row0 + r) * C + kt + kl;
            insf[r][kl] = x0[gi] + m[gi];
        }
        __syncthreads();
#pragma unroll
        for (int kl = 0; kl < 32; ++kl) {
            float wv = Ws[kl][col];
#pragma unroll
            for (int r = 0; r < 16; ++r)
                acc[r] += insf[rg * 16 + r][kl] * wv;
        }
        __syncthreads();
    }
#pragma unroll
    for (int r = 0; r < 16; ++r)
        out[(size_t)(row0 + rg * 16 + r) * C + col] = acc[r] + bias;
}

extern "C" void kernel_launch(void* const* d_in, const int* in_sizes, int n_in,
                              void* d_out, int out_size, void* d_ws, size_t ws_size,
                              hipStream_t stream) {
    const float* x0 = (const float*)d_in[0];
    const int* nidx = (const int*)d_in[1];
    const int* eidx = (const int*)d_in[2];
    const float* W  = (const float*)d_in[3];
    const float* b  = (const float*)d_in[4];

    float* out0 = (float*)d_out;
    float* x1   = out0 + (size_t)N_NODES * C;
    int nnz = in_sizes[1];

    // ---- workspace layout, each region 64B-aligned ----
    auto align64 = [](char* q) {
        return (char*)(((uintptr_t)q + 63) & ~(uintptr_t)63);
    };
    char* p = (char*)d_ws;
    uint64_t* pe = (uint64_t*)p;                       // pairs region, reused as x0h
    uint64_t* pn = pe + nnz;
    unsigned int* x0h = (unsigned int*)pe;             // N_NODES*64 uints fits in pairs region
    p = align64((char*)(pn + nnz));
    int* e_list = (int*)p; p = align64(p + (size_t)nnz * 4);
    int* n_list = (int*)p; p = align64(p + (size_t)nnz * 4);
    int* eoff   = (int*)p; p = align64(p + (size_t)(N_EDGES + 1) * 4);
    int* noff   = (int*)p; p = align64(p + (size_t)(N_NODES + 1) * 4);
    int* Ceh    = (int*)p;                              // Ceh+Cnh contiguous (one memset)
    int* Cnh    = Ceh + NB;
    p = align64((char*)(Cnh + NB));
    int* Cecur  = (int*)p; p = align64(p + NB * 4);
    int* Cncur  = (int*)p; p = align64(p + NB * 4);
    unsigned int* x1h = (unsigned int*)p; p = align64(p + (size_t)N_EDGES * 64 * 4);
    unsigned int* Whu = (unsigned int*)p; p = align64(p + (size_t)C * C / 2 * 4);
    size_t needed = (size_t)(p - (char*)d_ws);

    if (ws_size < needed) {
        float* m = (float*)d_ws;
        hipMemsetAsync(x1, 0, (size_t)N_EDGES * C * sizeof(float), stream);
        hipMemsetAsync(m,  0, (size_t)N_NODES * C * sizeof(float), stream);
        int blocks = (nnz + 7) / 8;
        scatter_rows<<<blocks, 256, 0, stream>>>((const float4*)x0, nidx, eidx, x1, nnz);
        scatter_rows<<<blocks, 256, 0, stream>>>((const float4*)x1, eidx, nidx, m, nnz);
        gin_gemm<<<N_NODES / 32, 256, 0, stream>>>(x0, m, W, b, out0);
        return;
    }

    int pblocks = (nnz + 4095) / 4096;

    // ---- CSR build: coarse LDS hist -> tiny scan -> partition -> per-bucket LDS sort ----
    hipMemsetAsync(Ceh, 0, 2 * NB * sizeof(int), stream);
    coarse_hist<<<pblocks, 256, 0, stream>>>(nidx, eidx, Ceh, Cnh, nnz);
    coarse_scan<<<1, 256, 0, stream>>>(Ceh, Cnh, Cecur, Cncur);
    partition_kernel<<<pblocks, 256, 0, stream>>>(
        nidx, eidx, Cecur, Cncur, pe, pn, nnz);
    bucket_scatter_ex<<<2 * NB, 256, 0, stream>>>(
        pe, pn, Cecur, Cncur, e_list, n_list, eoff, noff);

    // ---- bf16 copies (x0h overwrites pairs region AFTER scatters consumed it) ----
    conv_bf16<<<(N_NODES * 64 + 255) / 256, 256, 0, stream>>>(
        (const float2*)x0, x0h, N_NODES * 64);
    conv_bf16<<<(C * C / 2 + 255) / 256, 256, 0, stream>>>(
        (const float2*)W, Whu, C * C / 2);

    // ---- step 1: x1 (fp32 out) + x1h (bf16) ----
    seg_sum<<<(N_EDGES * 64 + 255) / 256, 256, 0, stream>>>(
        x0h, e_list, eoff, (float2*)x1, x1h, N_EDGES);

    // ---- steps 2+3 fused ----
    gin_fused<<<N_NODES / 32, 256, 0, stream>>>(
        (const float2*)x0, x1h, n_list, noff,
        (const unsigned short*)Whu, b, out0);
}